// Round 1
// baseline (562.426 us; speedup 1.0000x reference)
//
#include <hip/hip_runtime.h>
#include <math.h>

typedef __attribute__((ext_vector_type(8))) short bf16x8;
typedef __attribute__((ext_vector_type(4))) float f32x4;
typedef __attribute__((ext_vector_type(8))) unsigned short u16x8;

#define DEVFN __device__ __forceinline__

DEVFN unsigned short f2bf(float f) {
    unsigned int u = __float_as_uint(f);
    u += 0x7fffu + ((u >> 16) & 1u);   // RNE; inputs are finite
    return (unsigned short)(u >> 16);
}

// ---------------- elementwise cast f32 -> bf16, 8 elems/thread ----------------
__global__ void cast_f32_bf16_kernel(const float* __restrict__ in,
                                     unsigned short* __restrict__ out, int n8) {
    int i = blockIdx.x * blockDim.x + threadIdx.x;
    if (i >= n8) return;
    const float4* p = reinterpret_cast<const float4*>(in) + (size_t)i * 2;
    float4 a = p[0], b = p[1];
    u16x8 o;
    o[0] = f2bf(a.x); o[1] = f2bf(a.y); o[2] = f2bf(a.z); o[3] = f2bf(a.w);
    o[4] = f2bf(b.x); o[5] = f2bf(b.y); o[6] = f2bf(b.z); o[7] = f2bf(b.w);
    reinterpret_cast<u16x8*>(out)[i] = o;
}

// ---------------- tiled transpose -> bf16 ----------------
DEVFN unsigned short to_bf16_bits(float f) { return f2bf(f); }
DEVFN unsigned short to_bf16_bits(unsigned short u) { return u; }

template <typename T>
__global__ void transpose_to_bf16_kernel(const T* __restrict__ in,
                                         unsigned short* __restrict__ out,
                                         int R, int C) {
    __shared__ unsigned short tile[32][34];
    int c0 = blockIdx.x * 32, r0 = blockIdx.y * 32;
    int tx = threadIdx.x, ty = threadIdx.y;  // (32,8)
#pragma unroll
    for (int i = 0; i < 32; i += 8)
        tile[ty + i][tx] = to_bf16_bits(in[(size_t)(r0 + ty + i) * C + c0 + tx]);
    __syncthreads();
#pragma unroll
    for (int i = 0; i < 32; i += 8)
        out[(size_t)(c0 + ty + i) * R + r0 + tx] = tile[tx][ty + i];
}

// ---------------- GEMM: C = epilogue(A @ B^T) ----------------
// A: (M,K) bf16 row-major, lda. B: (N,K) bf16 row-major, ldb. K % 64 == 0,
// M,N % 128 == 0. 128x128 tile, 4 waves (2x2), each wave 64x64 via 4x4
// mfma_f32_16x16x32_bf16 fragments. LDS tiles XOR-swizzled (st-16B chunks,
// chunk ^= row&7) with linear global_load_lds dest + pre-swizzled global src.
enum { EP_BF16_BIAS = 0, EP_BF16_DMUL = 1, EP_BF16_GELU = 2, EP_F32 = 3 };

template <int MODE>
__global__ __launch_bounds__(256) void gemm_bt_kernel(
    const unsigned short* __restrict__ A, int lda,
    const unsigned short* __restrict__ B, int ldb,
    void* __restrict__ Cv, int ldc, int K,
    const float* __restrict__ bias,
    const float* __restrict__ Dmul, int ldd, int beta) {
    __shared__ alignas(16) unsigned short As[128 * 64];
    __shared__ alignas(16) unsigned short Bs[128 * 64];

    // XCD-aware swizzle (all grids here are %8==0 -> bijective)
    unsigned nwg = gridDim.x * gridDim.y;
    unsigned bid = blockIdx.y * gridDim.x + blockIdx.x;
    unsigned cpx = nwg >> 3;
    bid = (bid & 7u) * cpx + (bid >> 3);
    unsigned bx = bid % gridDim.x, by = bid / gridDim.x;
    size_t m0 = (size_t)by * 128, n0 = (size_t)bx * 128;

    int tid = threadIdx.x;
    int lane = tid & 63, w = tid >> 6;
    int wr = w >> 1, wc = w & 1;

    f32x4 acc[4][4];
#pragma unroll
    for (int i = 0; i < 4; ++i)
#pragma unroll
        for (int j = 0; j < 4; ++j)
#pragma unroll
            for (int r = 0; r < 4; ++r) acc[i][j][r] = 0.f;

    const unsigned short* Ablk = A + m0 * lda;
    const unsigned short* Bblk = B + n0 * ldb;
    int srccol = ((lane & 7) ^ (lane >> 3)) * 8;  // pre-swizzled source chunk
    int srow = w * 32 + (lane >> 3);
    unsigned short* ldsA = As + w * 2048;  // wave-uniform LDS bases (bytes w*4096)
    unsigned short* ldsB = Bs + w * 2048;

    int nkt = K >> 6;
    for (int kt = 0; kt < nkt; ++kt) {
        int k0 = kt << 6;
#pragma unroll
        for (int i = 0; i < 4; ++i) {
            __builtin_amdgcn_global_load_lds(
                (const __attribute__((address_space(1))) void*)(Ablk + (size_t)(srow + i * 8) * lda + k0 + srccol),
                (__attribute__((address_space(3))) void*)(ldsA + i * 512), 16, 0, 0);
            __builtin_amdgcn_global_load_lds(
                (const __attribute__((address_space(1))) void*)(Bblk + (size_t)(srow + i * 8) * ldb + k0 + srccol),
                (__attribute__((address_space(3))) void*)(ldsB + i * 512), 16, 0, 0);
        }
        __syncthreads();  // compiler drains vmcnt before barrier

        const bf16x8* Ap = reinterpret_cast<const bf16x8*>(As);
        const bf16x8* Bp = reinterpret_cast<const bf16x8*>(Bs);
#pragma unroll
        for (int kk = 0; kk < 2; ++kk) {
            bf16x8 af[4], bfr[4];
#pragma unroll
            for (int mi = 0; mi < 4; ++mi) {
                int row = wr * 64 + mi * 16 + (lane & 15);
                int slot = ((kk << 2) + (lane >> 4)) ^ (row & 7);
                af[mi] = Ap[row * 8 + slot];
            }
#pragma unroll
            for (int ni = 0; ni < 4; ++ni) {
                int row = wc * 64 + ni * 16 + (lane & 15);
                int slot = ((kk << 2) + (lane >> 4)) ^ (row & 7);
                bfr[ni] = Bp[row * 8 + slot];
            }
#pragma unroll
            for (int mi = 0; mi < 4; ++mi)
#pragma unroll
                for (int ni = 0; ni < 4; ++ni)
                    acc[mi][ni] = __builtin_amdgcn_mfma_f32_16x16x32_bf16(
                        af[mi], bfr[ni], acc[mi][ni], 0, 0, 0);
        }
        __syncthreads();
    }

    // epilogue: C/D frag layout col=lane&15, row=(lane>>4)*4+reg  [m89-verified]
    int cif = lane & 15;
    int rif = (lane >> 4) << 2;
#pragma unroll
    for (int mi = 0; mi < 4; ++mi) {
#pragma unroll
        for (int ni = 0; ni < 4; ++ni) {
            size_t gcol = n0 + wc * 64 + ni * 16 + cif;
            float bval = 0.f;
            if (MODE == EP_BF16_BIAS || MODE == EP_BF16_GELU || MODE == EP_F32)
                if (bias) bval = bias[gcol];
#pragma unroll
            for (int r = 0; r < 4; ++r) {
                size_t grow = m0 + wr * 64 + mi * 16 + rif + r;
                float val = acc[mi][ni][r] + bval;
                if (MODE == EP_BF16_DMUL)
                    val = acc[mi][ni][r] * Dmul[grow * (size_t)ldd + gcol];
                if (MODE == EP_BF16_GELU)
                    val = 0.5f * val * (1.f + erff(val * 0.70710678118654752f));
                if (MODE == EP_F32) {
                    float* Cf = (float*)Cv;
                    size_t idx = grow * (size_t)ldc + gcol;
                    if (beta) val += Cf[idx];
                    Cf[idx] = val;
                } else {
                    ((unsigned short*)Cv)[grow * (size_t)ldc + gcol] = f2bf(val);
                }
            }
        }
    }
}

// ---------------- PReLU + GroupNorm(G=16, 32 ch/group) ----------------
// one wave per row (512 ch): lane holds 8 ch; group g = lanes 4g..4g+3
__global__ void prelu_gn_kernel(const float* __restrict__ x,
                                const float* __restrict__ pa,
                                const float* __restrict__ gw,
                                const float* __restrict__ gb,
                                float* __restrict__ out) {
    int row = blockIdx.x * 4 + (threadIdx.x >> 6);
    int lane = threadIdx.x & 63;
    int c0 = lane * 8;
    const float4* px = reinterpret_cast<const float4*>(x + (size_t)row * 512 + c0);
    float4 v[2] = {px[0], px[1]};
    const float4* pav = reinterpret_cast<const float4*>(pa + c0);
    float4 av[2] = {pav[0], pav[1]};
    float* vp = (float*)v;
    float* ap = (float*)av;
    float s = 0.f, ss = 0.f;
#pragma unroll
    for (int j = 0; j < 8; ++j) {
        float t = vp[j];
        t = t >= 0.f ? t : ap[j] * t;
        vp[j] = t;
        s += t;
        ss += t * t;
    }
    s += __shfl_xor(s, 1); ss += __shfl_xor(ss, 1);
    s += __shfl_xor(s, 2); ss += __shfl_xor(ss, 2);
    float mu = s * (1.f / 32.f);
    float inv = rsqrtf(ss * (1.f / 32.f) - mu * mu + 1e-5f);
    const float4* gwv = reinterpret_cast<const float4*>(gw + c0);
    const float4* gbv = reinterpret_cast<const float4*>(gb + c0);
    float4 wv[2] = {gwv[0], gwv[1]}, bv[2] = {gbv[0], gbv[1]};
    float* wp = (float*)wv;
    float* bp = (float*)bv;
    float4 o[2];
    float* op = (float*)o;
#pragma unroll
    for (int j = 0; j < 8; ++j) op[j] = (vp[j] - mu) * inv * wp[j] + bp[j];
    float4* po = reinterpret_cast<float4*>(out + (size_t)row * 512 + c0);
    po[0] = o[0];
    po[1] = o[1];
}

extern "C" void kernel_launch(void* const* d_in, const int* in_sizes, int n_in,
                              void* d_out, int out_size, void* d_ws, size_t ws_size,
                              hipStream_t stream) {
    constexpr int Nn = 8192, IND = 512, INTER = 512, HID = 1024, OUTD = 512;
    constexpr int CH = 2048;  // scores column-chunk
    const float* h   = (const float*)d_in[0];
    const float* Dm  = (const float*)d_in[1];
    const float* hp  = (const float*)d_in[2];
    const float* Qw  = (const float*)d_in[3];
    const float* Qb  = (const float*)d_in[4];
    const float* Kw  = (const float*)d_in[5];
    const float* Kb  = (const float*)d_in[6];
    const float* Vw  = (const float*)d_in[7];
    const float* Vb  = (const float*)d_in[8];
    const float* Rw  = (const float*)d_in[9];
    const float* Rb  = (const float*)d_in[10];
    const float* Cw  = (const float*)d_in[11];
    const float* Cb  = (const float*)d_in[12];
    const float* Pw  = (const float*)d_in[13];
    const float* Pb  = (const float*)d_in[14];
    const float* pa  = (const float*)d_in[15];
    const float* gwt = (const float*)d_in[16];
    const float* gbt = (const float*)d_in[17];
    (void)in_sizes; (void)n_in; (void)out_size; (void)ws_size;

    char* ws = (char*)d_ws;
    size_t cur = 0;
    auto alloc = [&](size_t bytes) -> void* {
        void* p = ws + cur;
        cur += (bytes + 255) & ~(size_t)255;
        return p;
    };
    unsigned short* h_bf  = (unsigned short*)alloc((size_t)Nn * IND * 2);
    unsigned short* hp_bf = (unsigned short*)alloc((size_t)Nn * OUTD * 2);
    unsigned short* QwT   = (unsigned short*)alloc((size_t)IND * INTER * 2);
    unsigned short* KwT   = (unsigned short*)alloc((size_t)IND * INTER * 2);
    unsigned short* VwT   = (unsigned short*)alloc((size_t)IND * INTER * 2);
    unsigned short* RwT   = (unsigned short*)alloc((size_t)INTER * HID * 2);
    unsigned short* CwT   = (unsigned short*)alloc((size_t)OUTD * HID * 2);
    unsigned short* PwT   = (unsigned short*)alloc((size_t)2 * HID * OUTD * 2);
    unsigned short* Qm    = (unsigned short*)alloc((size_t)Nn * INTER * 2);
    unsigned short* Km    = (unsigned short*)alloc((size_t)Nn * INTER * 2);
    unsigned short* Vm    = (unsigned short*)alloc((size_t)Nn * INTER * 2);
    unsigned short* VTm   = (unsigned short*)alloc((size_t)Nn * INTER * 2);
    unsigned short* Sm    = (unsigned short*)alloc((size_t)Nn * CH * 2);   // scores chunk; reused as `combined`
    float*          hret32 = (float*)alloc((size_t)Nn * INTER * 4);
    unsigned short* hretbf = (unsigned short*)alloc((size_t)Nn * INTER * 2);
    // overlays (lifetime-disjoint): x over Q||K (16MB), combined over Sm (32MB)
    float* xbuf = (float*)Qm;
    unsigned short* comb = Sm;

    dim3 tb(32, 8);
    int n8 = Nn * IND / 8;
    cast_f32_bf16_kernel<<<n8 / 256, 256, 0, stream>>>(h, h_bf, n8);
    cast_f32_bf16_kernel<<<n8 / 256, 256, 0, stream>>>(hp, hp_bf, n8);
    transpose_to_bf16_kernel<float><<<dim3(INTER / 32, IND / 32), tb, 0, stream>>>(Qw, QwT, IND, INTER);
    transpose_to_bf16_kernel<float><<<dim3(INTER / 32, IND / 32), tb, 0, stream>>>(Kw, KwT, IND, INTER);
    transpose_to_bf16_kernel<float><<<dim3(INTER / 32, IND / 32), tb, 0, stream>>>(Vw, VwT, IND, INTER);
    transpose_to_bf16_kernel<float><<<dim3(HID / 32, INTER / 32), tb, 0, stream>>>(Rw, RwT, INTER, HID);
    transpose_to_bf16_kernel<float><<<dim3(HID / 32, OUTD / 32), tb, 0, stream>>>(Cw, CwT, OUTD, HID);
    transpose_to_bf16_kernel<float><<<dim3(OUTD / 32, 2 * HID / 32), tb, 0, stream>>>(Pw, PwT, 2 * HID, OUTD);

    // QKV projections (M=8192, N=512, K=512)
    gemm_bt_kernel<EP_BF16_BIAS><<<dim3(INTER / 128, Nn / 128), 256, 0, stream>>>(
        h_bf, IND, QwT, IND, Qm, INTER, IND, Qb, nullptr, 0, 0);
    gemm_bt_kernel<EP_BF16_BIAS><<<dim3(INTER / 128, Nn / 128), 256, 0, stream>>>(
        h_bf, IND, KwT, IND, Km, INTER, IND, Kb, nullptr, 0, 0);
    gemm_bt_kernel<EP_BF16_BIAS><<<dim3(INTER / 128, Nn / 128), 256, 0, stream>>>(
        h_bf, IND, VwT, IND, Vm, INTER, IND, Vb, nullptr, 0, 0);
    transpose_to_bf16_kernel<unsigned short><<<dim3(INTER / 32, Nn / 32), tb, 0, stream>>>(Vm, VTm, Nn, INTER);

    // retention: hret32 = sum_c [ (D .* (Q K^T))[:, c-chunk] @ V[c-chunk, :] ]
    for (int c = 0; c < Nn / CH; ++c) {
        int c0 = c * CH;
        gemm_bt_kernel<EP_BF16_DMUL><<<dim3(CH / 128, Nn / 128), 256, 0, stream>>>(
            Qm, INTER, Km + (size_t)c0 * INTER, INTER, Sm, CH, INTER,
            nullptr, Dm + c0, Nn, 0);
        gemm_bt_kernel<EP_F32><<<dim3(OUTD / 128, Nn / 128), 256, 0, stream>>>(
            Sm, CH, VTm + c0, Nn, hret32, OUTD, CH,
            nullptr, nullptr, 0, c > 0 ? 1 : 0);
    }
    cast_f32_bf16_kernel<<<(Nn * INTER / 8) / 256, 256, 0, stream>>>(hret32, hretbf, Nn * INTER / 8);

    // combined[:, :1024] = gelu(hret @ Rw + Rb);  combined[:, 1024:] = h' @ Cw + Cb
    gemm_bt_kernel<EP_BF16_GELU><<<dim3(HID / 128, Nn / 128), 256, 0, stream>>>(
        hretbf, INTER, RwT, INTER, comb, 2 * HID, INTER, Rb, nullptr, 0, 0);
    gemm_bt_kernel<EP_BF16_BIAS><<<dim3(HID / 128, Nn / 128), 256, 0, stream>>>(
        hp_bf, OUTD, CwT, OUTD, comb + HID, 2 * HID, OUTD, Cb, nullptr, 0, 0);

    // x = combined @ Pw + Pb  (fp32 out)
    gemm_bt_kernel<EP_F32><<<dim3(OUTD / 128, Nn / 128), 256, 0, stream>>>(
        comb, 2 * HID, PwT, 2 * HID, xbuf, OUTD, 2 * HID, Pb, nullptr, 0, 0);

    // PReLU + GroupNorm -> d_out
    prelu_gn_kernel<<<Nn / 4, 256, 0, stream>>>(xbuf, pa, gwt, gbt, (float*)d_out);
}

// Round 2
// 450.728 us; speedup vs baseline: 1.2478x; 1.2478x over previous
//
#include <hip/hip_runtime.h>
#include <math.h>

typedef __attribute__((ext_vector_type(8))) short bf16x8;
typedef __attribute__((ext_vector_type(4))) float f32x4;
typedef __attribute__((ext_vector_type(8))) unsigned short u16x8;

#define DEVFN __device__ __forceinline__

DEVFN unsigned short f2bf(float f) {
    unsigned int u = __float_as_uint(f);
    u += 0x7fffu + ((u >> 16) & 1u);   // RNE; inputs are finite
    return (unsigned short)(u >> 16);
}

// ---------------- elementwise cast f32 -> bf16, 8 elems/thread ----------------
__global__ void cast_f32_bf16_kernel(const float* __restrict__ in,
                                     unsigned short* __restrict__ out, int n8) {
    int i = blockIdx.x * blockDim.x + threadIdx.x;
    if (i >= n8) return;
    const float4* p = reinterpret_cast<const float4*>(in) + (size_t)i * 2;
    float4 a = p[0], b = p[1];
    u16x8 o;
    o[0] = f2bf(a.x); o[1] = f2bf(a.y); o[2] = f2bf(a.z); o[3] = f2bf(a.w);
    o[4] = f2bf(b.x); o[5] = f2bf(b.y); o[6] = f2bf(b.z); o[7] = f2bf(b.w);
    reinterpret_cast<u16x8*>(out)[i] = o;
}

// ---------------- sum 4 fp32 partials -> bf16 ----------------
__global__ void sum4_cast_kernel(const float* __restrict__ p, size_t stride,
                                 unsigned short* __restrict__ out, int n8) {
    int i = blockIdx.x * blockDim.x + threadIdx.x;
    if (i >= n8) return;
    const float4* a = reinterpret_cast<const float4*>(p) + (size_t)i * 2;
    const float4* b = reinterpret_cast<const float4*>(p + stride) + (size_t)i * 2;
    const float4* c = reinterpret_cast<const float4*>(p + 2 * stride) + (size_t)i * 2;
    const float4* d = reinterpret_cast<const float4*>(p + 3 * stride) + (size_t)i * 2;
    u16x8 o;
#pragma unroll
    for (int j = 0; j < 2; ++j) {
        float4 va = a[j], vb = b[j], vc = c[j], vd = d[j];
        o[4 * j + 0] = f2bf(va.x + vb.x + vc.x + vd.x);
        o[4 * j + 1] = f2bf(va.y + vb.y + vc.y + vd.y);
        o[4 * j + 2] = f2bf(va.z + vb.z + vc.z + vd.z);
        o[4 * j + 3] = f2bf(va.w + vb.w + vc.w + vd.w);
    }
    reinterpret_cast<u16x8*>(out)[i] = o;
}

// ---------------- concat 3 bias vectors (512 each) ----------------
__global__ void concat_bias_kernel(const float* __restrict__ a,
                                   const float* __restrict__ b,
                                   const float* __restrict__ c,
                                   float* __restrict__ o) {
    int i = blockIdx.x * blockDim.x + threadIdx.x;
    if (i >= 1536) return;
    o[i] = i < 512 ? a[i] : (i < 1024 ? b[i - 512] : c[i - 1024]);
}

// ---------------- tiled transpose -> bf16 (with leading dims) ----------------
DEVFN unsigned short to_bf16_bits(float f) { return f2bf(f); }
DEVFN unsigned short to_bf16_bits(unsigned short u) { return u; }

template <typename T>
__global__ void transpose_to_bf16_kernel(const T* __restrict__ in, int ldin,
                                         unsigned short* __restrict__ out, int ldout) {
    __shared__ unsigned short tile[32][34];
    int c0 = blockIdx.x * 32, r0 = blockIdx.y * 32;
    int tx = threadIdx.x, ty = threadIdx.y;  // (32,8)
#pragma unroll
    for (int i = 0; i < 32; i += 8)
        tile[ty + i][tx] = to_bf16_bits(in[(size_t)(r0 + ty + i) * ldin + c0 + tx]);
    __syncthreads();
#pragma unroll
    for (int i = 0; i < 32; i += 8)
        out[(size_t)(c0 + ty + i) * ldout + r0 + tx] = tile[tx][ty + i];
}

// ---------------- GEMM: C = epilogue(A @ B^T) ----------------
// A: (M,K) bf16 row-major lda. B: (N,K) bf16 row-major ldb. K%64==0, M,N%128==0.
// 128x128 tile, 4 waves (2x2), 4x4 mfma_f32_16x16x32_bf16 frags/wave.
// LDS XOR-swizzled via pre-swizzled global src + linear global_load_lds dest.
// blockIdx.z: K-split (A,B advance z*K cols; EP_F32 writes partial z*zstride).
enum { EP_BF16_BIAS = 0, EP_BF16_DMUL = 1, EP_BF16_GELU = 2, EP_F32 = 3, EP_PRELU_GN = 4 };

template <int MODE>
__global__ __launch_bounds__(256) void gemm_bt_kernel(
    const unsigned short* __restrict__ A, int lda,
    const unsigned short* __restrict__ B, int ldb,
    void* __restrict__ Cv, int ldc, int K,
    const float* __restrict__ bias,
    const float* __restrict__ Dmul, int ldd,
    const float* __restrict__ PA, const float* __restrict__ GW,
    const float* __restrict__ GB, size_t zstride) {
    __shared__ alignas(16) unsigned short As[128 * 64];
    __shared__ alignas(16) unsigned short Bs[128 * 64];

    // XCD-aware swizzle (all 2D grids here are %8==0 -> bijective)
    unsigned nwg = gridDim.x * gridDim.y;
    unsigned bid = blockIdx.y * gridDim.x + blockIdx.x;
    unsigned cpx = nwg >> 3;
    bid = (bid & 7u) * cpx + (bid >> 3);
    unsigned bx = bid % gridDim.x, by = bid / gridDim.x;
    size_t m0 = (size_t)by * 128, n0 = (size_t)bx * 128;

    size_t koff = (size_t)blockIdx.z * K;
    A += koff;
    B += koff;

    int tid = threadIdx.x;
    int lane = tid & 63, w = tid >> 6;
    int wr = w >> 1, wc = w & 1;

    f32x4 acc[4][4];
#pragma unroll
    for (int i = 0; i < 4; ++i)
#pragma unroll
        for (int j = 0; j < 4; ++j)
#pragma unroll
            for (int r = 0; r < 4; ++r) acc[i][j][r] = 0.f;

    const unsigned short* Ablk = A + m0 * lda;
    const unsigned short* Bblk = B + n0 * ldb;
    int srccol = ((lane & 7) ^ (lane >> 3)) * 8;  // pre-swizzled source chunk
    int srow = w * 32 + (lane >> 3);
    unsigned short* ldsA = As + w * 2048;  // wave-uniform LDS bases
    unsigned short* ldsB = Bs + w * 2048;

    int nkt = K >> 6;
    for (int kt = 0; kt < nkt; ++kt) {
        int k0 = kt << 6;
#pragma unroll
        for (int i = 0; i < 4; ++i) {
            __builtin_amdgcn_global_load_lds(
                (const __attribute__((address_space(1))) void*)(Ablk + (size_t)(srow + i * 8) * lda + k0 + srccol),
                (__attribute__((address_space(3))) void*)(ldsA + i * 512), 16, 0, 0);
            __builtin_amdgcn_global_load_lds(
                (const __attribute__((address_space(1))) void*)(Bblk + (size_t)(srow + i * 8) * ldb + k0 + srccol),
                (__attribute__((address_space(3))) void*)(ldsB + i * 512), 16, 0, 0);
        }
        __syncthreads();

        const bf16x8* Ap = reinterpret_cast<const bf16x8*>(As);
        const bf16x8* Bp = reinterpret_cast<const bf16x8*>(Bs);
#pragma unroll
        for (int kk = 0; kk < 2; ++kk) {
            bf16x8 af[4], bfr[4];
#pragma unroll
            for (int mi = 0; mi < 4; ++mi) {
                int row = wr * 64 + mi * 16 + (lane & 15);
                int slot = ((kk << 2) + (lane >> 4)) ^ (row & 7);
                af[mi] = Ap[row * 8 + slot];
            }
#pragma unroll
            for (int ni = 0; ni < 4; ++ni) {
                int row = wc * 64 + ni * 16 + (lane & 15);
                int slot = ((kk << 2) + (lane >> 4)) ^ (row & 7);
                bfr[ni] = Bp[row * 8 + slot];
            }
#pragma unroll
            for (int mi = 0; mi < 4; ++mi)
#pragma unroll
                for (int ni = 0; ni < 4; ++ni)
                    acc[mi][ni] = __builtin_amdgcn_mfma_f32_16x16x32_bf16(
                        af[mi], bfr[ni], acc[mi][ni], 0, 0, 0);
        }
        __syncthreads();
    }

    // epilogue: C/D frag layout col=lane&15, row=(lane>>4)*4+reg  [m89-verified]
    int cif = lane & 15;
    int rif = (lane >> 4) << 2;

    if (MODE == EP_PRELU_GN) {
        // x = acc + Pb; PReLU; GroupNorm over 32-ch groups (= ni pairs), fp32 out.
        float* Cf = (float*)Cv;
        float pbv[4], pav[4], gwv[4], gbv[4];
        size_t gcolv[4];
#pragma unroll
        for (int ni = 0; ni < 4; ++ni) {
            gcolv[ni] = n0 + wc * 64 + ni * 16 + cif;
            pbv[ni] = bias[gcolv[ni]];
            pav[ni] = PA[gcolv[ni]];
            gwv[ni] = GW[gcolv[ni]];
            gbv[ni] = GB[gcolv[ni]];
        }
#pragma unroll
        for (int mi = 0; mi < 4; ++mi) {
#pragma unroll
            for (int ni = 0; ni < 4; ++ni)
#pragma unroll
                for (int r = 0; r < 4; ++r) {
                    float v = acc[mi][ni][r] + pbv[ni];
                    acc[mi][ni][r] = v >= 0.f ? v : pav[ni] * v;
                }
#pragma unroll
            for (int p = 0; p < 2; ++p) {
                float s[4], ss[4];
#pragma unroll
                for (int r = 0; r < 4; ++r) {
                    float a0 = acc[mi][2 * p][r], a1 = acc[mi][2 * p + 1][r];
                    s[r] = a0 + a1;
                    ss[r] = a0 * a0 + a1 * a1;
                }
#pragma unroll
                for (int msk = 1; msk < 16; msk <<= 1)
#pragma unroll
                    for (int r = 0; r < 4; ++r) {
                        s[r] += __shfl_xor(s[r], msk);
                        ss[r] += __shfl_xor(ss[r], msk);
                    }
#pragma unroll
                for (int r = 0; r < 4; ++r) {
                    float mu = s[r] * (1.f / 32.f);
                    float inv = rsqrtf(ss[r] * (1.f / 32.f) - mu * mu + 1e-5f);
                    size_t grow = m0 + wr * 64 + mi * 16 + rif + r;
#pragma unroll
                    for (int q = 0; q < 2; ++q) {
                        int ni = 2 * p + q;
                        Cf[grow * (size_t)ldc + gcolv[ni]] =
                            (acc[mi][ni][r] - mu) * inv * gwv[ni] + gbv[ni];
                    }
                }
            }
        }
        return;
    }

#pragma unroll
    for (int mi = 0; mi < 4; ++mi) {
#pragma unroll
        for (int ni = 0; ni < 4; ++ni) {
            size_t gcol = n0 + wc * 64 + ni * 16 + cif;
            float bval = 0.f;
            if (MODE == EP_BF16_BIAS || MODE == EP_BF16_GELU || MODE == EP_F32)
                if (bias) bval = bias[gcol];
#pragma unroll
            for (int r = 0; r < 4; ++r) {
                size_t grow = m0 + wr * 64 + mi * 16 + rif + r;
                float val = acc[mi][ni][r] + bval;
                if (MODE == EP_BF16_DMUL)
                    val = acc[mi][ni][r] * Dmul[grow * (size_t)ldd + gcol];
                if (MODE == EP_BF16_GELU)
                    val = 0.5f * val * (1.f + erff(val * 0.70710678118654752f));
                if (MODE == EP_F32) {
                    float* Cf = (float*)Cv + blockIdx.z * zstride;
                    Cf[grow * (size_t)ldc + gcol] = val;
                } else {
                    ((unsigned short*)Cv)[grow * (size_t)ldc + gcol] = f2bf(val);
                }
            }
        }
    }
}

extern "C" void kernel_launch(void* const* d_in, const int* in_sizes, int n_in,
                              void* d_out, int out_size, void* d_ws, size_t ws_size,
                              hipStream_t stream) {
    constexpr int Nn = 8192, IND = 512, INTER = 512, HID = 1024, OUTD = 512;
    const float* h   = (const float*)d_in[0];
    const float* Dm  = (const float*)d_in[1];
    const float* hp  = (const float*)d_in[2];
    const float* Qw  = (const float*)d_in[3];
    const float* Qb  = (const float*)d_in[4];
    const float* Kw  = (const float*)d_in[5];
    const float* Kb  = (const float*)d_in[6];
    const float* Vw  = (const float*)d_in[7];
    const float* Vb  = (const float*)d_in[8];
    const float* Rw  = (const float*)d_in[9];
    const float* Rb  = (const float*)d_in[10];
    const float* Cw  = (const float*)d_in[11];
    const float* Cb  = (const float*)d_in[12];
    const float* Pw  = (const float*)d_in[13];
    const float* Pb  = (const float*)d_in[14];
    const float* pa  = (const float*)d_in[15];
    const float* gwt = (const float*)d_in[16];
    const float* gbt = (const float*)d_in[17];
    (void)in_sizes; (void)n_in; (void)out_size; (void)ws_size;

    char* ws = (char*)d_ws;
    size_t cur = 0;
    auto alloc = [&](size_t bytes) -> void* {
        void* p = ws + cur;
        cur += (bytes + 255) & ~(size_t)255;
        return p;
    };
    unsigned short* h_bf   = (unsigned short*)alloc((size_t)Nn * IND * 2);
    unsigned short* hp_bf  = (unsigned short*)alloc((size_t)Nn * OUTD * 2);
    unsigned short* QKVwT  = (unsigned short*)alloc((size_t)3 * INTER * IND * 2);
    float*          qkvb   = (float*)alloc((size_t)3 * INTER * 4);
    unsigned short* RwT    = (unsigned short*)alloc((size_t)INTER * HID * 2);
    unsigned short* CwT    = (unsigned short*)alloc((size_t)OUTD * HID * 2);
    unsigned short* PwT    = (unsigned short*)alloc((size_t)2 * HID * OUTD * 2);
    unsigned short* QKVm   = (unsigned short*)alloc((size_t)Nn * 3 * INTER * 2);
    unsigned short* VTm    = (unsigned short*)alloc((size_t)Nn * INTER * 2);
    unsigned short* Sm     = (unsigned short*)alloc((size_t)Nn * Nn * 2);      // 134 MB scores
    float*          hret32 = (float*)alloc((size_t)4 * Nn * INTER * 4);        // K-split partials
    unsigned short* hretbf = (unsigned short*)alloc((size_t)Nn * INTER * 2);
    unsigned short* comb   = Sm;  // overlay: combined (8192x2048 bf16) over dead scores

    unsigned short* Qm = QKVm;
    unsigned short* Km = QKVm + INTER;
    unsigned short* Vm = QKVm + 2 * INTER;
    const int ldqkv = 3 * INTER;

    dim3 tb(32, 8);
    int n8 = Nn * IND / 8;
    cast_f32_bf16_kernel<<<n8 / 256, 256, 0, stream>>>(h, h_bf, n8);
    cast_f32_bf16_kernel<<<n8 / 256, 256, 0, stream>>>(hp, hp_bf, n8);
    transpose_to_bf16_kernel<float><<<dim3(INTER / 32, IND / 32), tb, 0, stream>>>(Qw, INTER, QKVwT, IND);
    transpose_to_bf16_kernel<float><<<dim3(INTER / 32, IND / 32), tb, 0, stream>>>(Kw, INTER, QKVwT + (size_t)INTER * IND, IND);
    transpose_to_bf16_kernel<float><<<dim3(INTER / 32, IND / 32), tb, 0, stream>>>(Vw, INTER, QKVwT + (size_t)2 * INTER * IND, IND);
    concat_bias_kernel<<<6, 256, 0, stream>>>(Qb, Kb, Vb, qkvb);
    transpose_to_bf16_kernel<float><<<dim3(HID / 32, INTER / 32), tb, 0, stream>>>(Rw, HID, RwT, INTER);
    transpose_to_bf16_kernel<float><<<dim3(HID / 32, OUTD / 32), tb, 0, stream>>>(Cw, HID, CwT, OUTD);
    transpose_to_bf16_kernel<float><<<dim3(OUTD / 32, 2 * HID / 32), tb, 0, stream>>>(Pw, OUTD, PwT, 2 * HID);

    // fused QKV projection: (8192 x 1536) = h @ [Qw|Kw|Vw] + [Qb|Kb|Vb]
    gemm_bt_kernel<EP_BF16_BIAS><<<dim3(3 * INTER / 128, Nn / 128), 256, 0, stream>>>(
        h_bf, IND, QKVwT, IND, QKVm, ldqkv, IND, qkvb, nullptr, 0, nullptr, nullptr, nullptr, 0);
    transpose_to_bf16_kernel<unsigned short><<<dim3(INTER / 32, Nn / 32), tb, 0, stream>>>(Vm, ldqkv, VTm, Nn);

    // stage2: scores = D .* (Q K^T), full 8192x8192 bf16
    gemm_bt_kernel<EP_BF16_DMUL><<<dim3(Nn / 128, Nn / 128), 256, 0, stream>>>(
        Qm, ldqkv, Km, ldqkv, Sm, Nn, INTER, nullptr, Dm, Nn, nullptr, nullptr, nullptr, 0);

    // stage3: hret = scores @ V, K-split x4 into fp32 partials
    gemm_bt_kernel<EP_F32><<<dim3(OUTD / 128, Nn / 128, 4), 256, 0, stream>>>(
        Sm, Nn, VTm, Nn, hret32, INTER, Nn / 4, nullptr, nullptr, 0,
        nullptr, nullptr, nullptr, (size_t)Nn * INTER);
    sum4_cast_kernel<<<(Nn * INTER / 8) / 256, 256, 0, stream>>>(
        hret32, (size_t)Nn * INTER, hretbf, Nn * INTER / 8);

    // combined[:, :1024] = gelu(hret @ Rw + Rb);  combined[:, 1024:] = h' @ Cw + Cb
    gemm_bt_kernel<EP_BF16_GELU><<<dim3(HID / 128, Nn / 128), 256, 0, stream>>>(
        hretbf, INTER, RwT, INTER, comb, 2 * HID, INTER, Rb, nullptr, 0, nullptr, nullptr, nullptr, 0);
    gemm_bt_kernel<EP_BF16_BIAS><<<dim3(HID / 128, Nn / 128), 256, 0, stream>>>(
        hp_bf, OUTD, CwT, OUTD, comb + HID, 2 * HID, OUTD, Cb, nullptr, 0, nullptr, nullptr, nullptr, 0);

    // x = combined @ Pw + Pb -> PReLU -> GroupNorm -> d_out (fp32)
    gemm_bt_kernel<EP_PRELU_GN><<<dim3(OUTD / 128, Nn / 128), 256, 0, stream>>>(
        comb, 2 * HID, PwT, 2 * HID, d_out, OUTD, 2 * HID, Pb, nullptr, 0, pa, gwt, gbt, 0);
}

// Round 3
// 422.616 us; speedup vs baseline: 1.3308x; 1.0665x over previous
//
#include <hip/hip_runtime.h>
#include <math.h>

typedef __attribute__((ext_vector_type(8))) short bf16x8;
typedef __attribute__((ext_vector_type(4))) float f32x4;
typedef __attribute__((ext_vector_type(8))) unsigned short u16x8;

#define DEVFN __device__ __forceinline__

DEVFN unsigned short f2bf(float f) {
    unsigned int u = __float_as_uint(f);
    u += 0x7fffu + ((u >> 16) & 1u);   // RNE; inputs are finite
    return (unsigned short)(u >> 16);
}

// ---------------- dual cast f32 -> bf16 (h and h'), 8 elems/thread ----------------
__global__ void cast2_kernel(const float* __restrict__ a, const float* __restrict__ b,
                             unsigned short* __restrict__ oa, unsigned short* __restrict__ ob,
                             int n8) {
    const float* in = blockIdx.y ? b : a;
    unsigned short* out = blockIdx.y ? ob : oa;
    int i = blockIdx.x * blockDim.x + threadIdx.x;
    if (i >= n8) return;
    const float4* p = reinterpret_cast<const float4*>(in) + (size_t)i * 2;
    float4 x = p[0], y = p[1];
    u16x8 o;
    o[0] = f2bf(x.x); o[1] = f2bf(x.y); o[2] = f2bf(x.z); o[3] = f2bf(x.w);
    o[4] = f2bf(y.x); o[5] = f2bf(y.y); o[6] = f2bf(y.z); o[7] = f2bf(y.w);
    reinterpret_cast<u16x8*>(out)[i] = o;
}

// ---------------- sum 4 fp32 partials -> bf16 ----------------
__global__ void sum4_cast_kernel(const float* __restrict__ p, size_t stride,
                                 unsigned short* __restrict__ out, int n8) {
    int i = blockIdx.x * blockDim.x + threadIdx.x;
    if (i >= n8) return;
    const float4* a = reinterpret_cast<const float4*>(p) + (size_t)i * 2;
    const float4* b = reinterpret_cast<const float4*>(p + stride) + (size_t)i * 2;
    const float4* c = reinterpret_cast<const float4*>(p + 2 * stride) + (size_t)i * 2;
    const float4* d = reinterpret_cast<const float4*>(p + 3 * stride) + (size_t)i * 2;
    u16x8 o;
#pragma unroll
    for (int j = 0; j < 2; ++j) {
        float4 va = a[j], vb = b[j], vc = c[j], vd = d[j];
        o[4 * j + 0] = f2bf(va.x + vb.x + vc.x + vd.x);
        o[4 * j + 1] = f2bf(va.y + vb.y + vc.y + vd.y);
        o[4 * j + 2] = f2bf(va.z + vb.z + vc.z + vd.z);
        o[4 * j + 3] = f2bf(va.w + vb.w + vc.w + vd.w);
    }
    reinterpret_cast<u16x8*>(out)[i] = o;
}

// ---------------- concat 3 bias vectors (512 each) ----------------
__global__ void concat_bias_kernel(const float* __restrict__ a,
                                   const float* __restrict__ b,
                                   const float* __restrict__ c,
                                   float* __restrict__ o) {
    int i = blockIdx.x * blockDim.x + threadIdx.x;
    if (i >= 1536) return;
    o[i] = i < 512 ? a[i] : (i < 1024 ? b[i - 512] : c[i - 1024]);
}

// ---------------- fused multi-matrix transpose f32 -> bf16 ----------------
struct TD { const float* in; unsigned short* out; int ldin, ldout, nbx, nby; };
struct TD6 { TD d[6]; };

__global__ void multi_transpose_kernel(TD6 t6) {
    TD d = t6.d[blockIdx.z];
    if ((int)blockIdx.x >= d.nbx || (int)blockIdx.y >= d.nby) return;
    __shared__ unsigned short tile[32][34];
    int c0 = blockIdx.x * 32, r0 = blockIdx.y * 32;
    int tx = threadIdx.x, ty = threadIdx.y;  // (32,8)
#pragma unroll
    for (int i = 0; i < 32; i += 8)
        tile[ty + i][tx] = f2bf(d.in[(size_t)(r0 + ty + i) * d.ldin + c0 + tx]);
    __syncthreads();
#pragma unroll
    for (int i = 0; i < 32; i += 8)
        d.out[(size_t)(c0 + ty + i) * d.ldout + r0 + tx] = tile[tx][ty + i];
}

// ---------------- bf16 matrix transpose (for V) ----------------
__global__ void transpose_bf16_kernel(const unsigned short* __restrict__ in, int ldin,
                                      unsigned short* __restrict__ out, int ldout) {
    __shared__ unsigned short tile[32][34];
    int c0 = blockIdx.x * 32, r0 = blockIdx.y * 32;
    int tx = threadIdx.x, ty = threadIdx.y;
#pragma unroll
    for (int i = 0; i < 32; i += 8)
        tile[ty + i][tx] = in[(size_t)(r0 + ty + i) * ldin + c0 + tx];
    __syncthreads();
#pragma unroll
    for (int i = 0; i < 32; i += 8)
        out[(size_t)(c0 + ty + i) * ldout + r0 + tx] = tile[tx][ty + i];
}

// ---------------- GEMM: C = epilogue(A @ B^T) ----------------
// 128x128 tile, 4 waves (2x2), 4x4 mfma_f32_16x16x32_bf16 frags/wave.
// Double-buffered LDS: stage(next) issued before compute(cur); ONE
// __syncthreads per K-iter (its vmcnt(0) drain lands after compute).
// LDS XOR-swizzled via pre-swizzled global src + linear global_load_lds dest.
enum { EP_BF16_BIAS = 0, EP_BF16_DMUL = 1, EP_F32 = 3, EP_PRELU_GN = 4, EP_DUAL = 5 };

template <int MODE>
__global__ __launch_bounds__(256, 2) void gemm_bt_kernel(
    const unsigned short* __restrict__ A, int lda,
    const unsigned short* __restrict__ B, int ldb,
    void* __restrict__ Cv, int ldc, int K,
    const float* __restrict__ bias,
    const float* __restrict__ Dmul, int ldd,
    const float* __restrict__ PA, const float* __restrict__ GW,
    const float* __restrict__ GB, size_t zstride,
    const unsigned short* __restrict__ A2,
    const unsigned short* __restrict__ B2,
    const float* __restrict__ bias2) {
    __shared__ alignas(16) unsigned short As[2][128 * 64];
    __shared__ alignas(16) unsigned short Bs[2][128 * 64];

    unsigned bx, by, zi;
    if (MODE == EP_F32) {
        // z-grouped XCD mapping: z-chunk -> XCD pair {2z,2z+1}; V z-slab stays L2-hot
        unsigned gx = gridDim.x;
        unsigned L = (blockIdx.z * gridDim.y + blockIdx.y) * gx + blockIdx.x;
        unsigned xcd = L & 7u, slot = L >> 3;
        zi = xcd >> 1;
        unsigned t = slot * 2 + (xcd & 1u);
        bx = t & (gx - 1);
        by = t / gx;
    } else {
        unsigned nwg = gridDim.x * gridDim.y;
        unsigned bid = blockIdx.y * gridDim.x + blockIdx.x;
        unsigned cpx = nwg >> 3;
        bid = (bid & 7u) * cpx + (bid >> 3);
        bx = bid % gridDim.x;
        by = bid / gridDim.x;
        zi = 0;
    }
    size_t m0 = (size_t)by * 128;
    size_t nB = (size_t)bx * 128;    // B row base / bias index base
    size_t ncol0 = nB;               // output column base

    const unsigned short* Ause = A;
    const unsigned short* Buse = B;
    const float* bias_use = bias;
    bool apply_gelu = false;
    if (MODE == EP_DUAL) {
        unsigned half = gridDim.x >> 1;
        if (bx >= half) {  // C-branch: h' @ Cw + Cb -> cols 1024..2047
            nB = (size_t)(bx - half) * 128;
            ncol0 = 1024 + nB;
            Ause = A2; Buse = B2; bias_use = bias2;
        } else {
            apply_gelu = true;
        }
    }

    int tid = threadIdx.x;
    int lane = tid & 63, w = tid >> 6;
    int wr = w >> 1, wc = w & 1;
    int cif = lane & 15;
    int rif = (lane >> 4) << 2;

    f32x4 acc[4][4];
#pragma unroll
    for (int i = 0; i < 4; ++i)
#pragma unroll
        for (int j = 0; j < 4; ++j)
#pragma unroll
            for (int r = 0; r < 4; ++r) acc[i][j][r] = 0.f;

    const unsigned short* Ablk = Ause + m0 * lda + (size_t)zi * K;
    const unsigned short* Bblk = Buse + nB * ldb + (size_t)zi * K;
    int srccol = ((lane & 7) ^ (lane >> 3)) * 8;  // pre-swizzled source chunk
    int srow = w * 32 + (lane >> 3);
    int nkt = K >> 6;

    float dreg[4][4][4];  // D prefetch (EP_BF16_DMUL only; else DCE'd)

    auto stage = [&](int buf, int kt) {
        int k0 = kt << 6;
        unsigned short* la = &As[buf][w * 2048];
        unsigned short* lb = &Bs[buf][w * 2048];
#pragma unroll
        for (int i = 0; i < 4; ++i) {
            __builtin_amdgcn_global_load_lds(
                (const __attribute__((address_space(1))) void*)(Ablk + (size_t)(srow + i * 8) * lda + k0 + srccol),
                (__attribute__((address_space(3))) void*)(la + i * 512), 16, 0, 0);
            __builtin_amdgcn_global_load_lds(
                (const __attribute__((address_space(1))) void*)(Bblk + (size_t)(srow + i * 8) * ldb + k0 + srccol),
                (__attribute__((address_space(3))) void*)(lb + i * 512), 16, 0, 0);
        }
    };

    stage(0, 0);
    __syncthreads();

    for (int kt = 0; kt < nkt; ++kt) {
        int cur = kt & 1;
        if (kt + 1 < nkt) {
            stage(cur ^ 1, kt + 1);
        } else if (MODE == EP_BF16_DMUL) {
            // last iter: prefetch D tile into regs, overlapped with final compute
#pragma unroll
            for (int mi = 0; mi < 4; ++mi)
#pragma unroll
                for (int ni = 0; ni < 4; ++ni)
#pragma unroll
                    for (int r = 0; r < 4; ++r)
                        dreg[mi][ni][r] =
                            Dmul[(m0 + wr * 64 + mi * 16 + rif + r) * (size_t)ldd +
                                 (ncol0 + wc * 64 + ni * 16 + cif)];
        }

        const bf16x8* Ap = reinterpret_cast<const bf16x8*>(As[cur]);
        const bf16x8* Bp = reinterpret_cast<const bf16x8*>(Bs[cur]);
#pragma unroll
        for (int kk = 0; kk < 2; ++kk) {
            bf16x8 af[4], bfr[4];
#pragma unroll
            for (int mi = 0; mi < 4; ++mi) {
                int row = wr * 64 + mi * 16 + (lane & 15);
                int slot = ((kk << 2) + (lane >> 4)) ^ (row & 7);
                af[mi] = Ap[row * 8 + slot];
            }
#pragma unroll
            for (int ni = 0; ni < 4; ++ni) {
                int row = wc * 64 + ni * 16 + (lane & 15);
                int slot = ((kk << 2) + (lane >> 4)) ^ (row & 7);
                bfr[ni] = Bp[row * 8 + slot];
            }
#pragma unroll
            for (int mi = 0; mi < 4; ++mi)
#pragma unroll
                for (int ni = 0; ni < 4; ++ni)
                    acc[mi][ni] = __builtin_amdgcn_mfma_f32_16x16x32_bf16(
                        af[mi], bfr[ni], acc[mi][ni], 0, 0, 0);
        }
        __syncthreads();
    }

    // epilogue: C/D frag layout col=lane&15, row=(lane>>4)*4+reg  [m89-verified]
    if (MODE == EP_PRELU_GN) {
        float* Cf = (float*)Cv;
        float pbv[4], pav[4], gwv[4], gbv[4];
        size_t gcolv[4];
#pragma unroll
        for (int ni = 0; ni < 4; ++ni) {
            gcolv[ni] = ncol0 + wc * 64 + ni * 16 + cif;
            pbv[ni] = bias[gcolv[ni]];
            pav[ni] = PA[gcolv[ni]];
            gwv[ni] = GW[gcolv[ni]];
            gbv[ni] = GB[gcolv[ni]];
        }
#pragma unroll
        for (int mi = 0; mi < 4; ++mi) {
#pragma unroll
            for (int ni = 0; ni < 4; ++ni)
#pragma unroll
                for (int r = 0; r < 4; ++r) {
                    float v = acc[mi][ni][r] + pbv[ni];
                    acc[mi][ni][r] = v >= 0.f ? v : pav[ni] * v;
                }
#pragma unroll
            for (int p = 0; p < 2; ++p) {
                float s[4], ss[4];
#pragma unroll
                for (int r = 0; r < 4; ++r) {
                    float a0 = acc[mi][2 * p][r], a1 = acc[mi][2 * p + 1][r];
                    s[r] = a0 + a1;
                    ss[r] = a0 * a0 + a1 * a1;
                }
#pragma unroll
                for (int msk = 1; msk < 16; msk <<= 1)
#pragma unroll
                    for (int r = 0; r < 4; ++r) {
                        s[r] += __shfl_xor(s[r], msk);
                        ss[r] += __shfl_xor(ss[r], msk);
                    }
#pragma unroll
                for (int r = 0; r < 4; ++r) {
                    float mu = s[r] * (1.f / 32.f);
                    float inv = rsqrtf(ss[r] * (1.f / 32.f) - mu * mu + 1e-5f);
                    size_t grow = m0 + wr * 64 + mi * 16 + rif + r;
#pragma unroll
                    for (int q = 0; q < 2; ++q) {
                        int ni = 2 * p + q;
                        Cf[grow * (size_t)ldc + gcolv[ni]] =
                            (acc[mi][ni][r] - mu) * inv * gwv[ni] + gbv[ni];
                    }
                }
            }
        }
        return;
    }

#pragma unroll
    for (int mi = 0; mi < 4; ++mi) {
#pragma unroll
        for (int ni = 0; ni < 4; ++ni) {
            size_t gcol = ncol0 + wc * 64 + ni * 16 + cif;
            size_t bcol = nB + wc * 64 + ni * 16 + cif;
            float bval = 0.f;
            if (MODE == EP_BF16_BIAS || MODE == EP_DUAL || MODE == EP_F32)
                if (bias_use) bval = bias_use[bcol];
#pragma unroll
            for (int r = 0; r < 4; ++r) {
                size_t grow = m0 + wr * 64 + mi * 16 + rif + r;
                float val = acc[mi][ni][r] + bval;
                if (MODE == EP_BF16_DMUL)
                    val = acc[mi][ni][r] * dreg[mi][ni][r];
                if (MODE == EP_DUAL && apply_gelu)
                    val = 0.5f * val * (1.f + erff(val * 0.70710678118654752f));
                if (MODE == EP_F32) {
                    float* Cf = (float*)Cv + zi * zstride;
                    Cf[grow * (size_t)ldc + gcol] = val;
                } else {
                    ((unsigned short*)Cv)[grow * (size_t)ldc + gcol] = f2bf(val);
                }
            }
        }
    }
}

extern "C" void kernel_launch(void* const* d_in, const int* in_sizes, int n_in,
                              void* d_out, int out_size, void* d_ws, size_t ws_size,
                              hipStream_t stream) {
    constexpr int Nn = 8192, IND = 512, INTER = 512, HID = 1024, OUTD = 512;
    const float* h   = (const float*)d_in[0];
    const float* Dm  = (const float*)d_in[1];
    const float* hp  = (const float*)d_in[2];
    const float* Qw  = (const float*)d_in[3];
    const float* Qb  = (const float*)d_in[4];
    const float* Kw  = (const float*)d_in[5];
    const float* Kb  = (const float*)d_in[6];
    const float* Vw  = (const float*)d_in[7];
    const float* Vb  = (const float*)d_in[8];
    const float* Rw  = (const float*)d_in[9];
    const float* Rb  = (const float*)d_in[10];
    const float* Cw  = (const float*)d_in[11];
    const float* Cb  = (const float*)d_in[12];
    const float* Pw  = (const float*)d_in[13];
    const float* Pb  = (const float*)d_in[14];
    const float* pa  = (const float*)d_in[15];
    const float* gwt = (const float*)d_in[16];
    const float* gbt = (const float*)d_in[17];
    (void)in_sizes; (void)n_in; (void)out_size; (void)ws_size;

    char* ws = (char*)d_ws;
    size_t cur = 0;
    auto alloc = [&](size_t bytes) -> void* {
        void* p = ws + cur;
        cur += (bytes + 255) & ~(size_t)255;
        return p;
    };
    unsigned short* h_bf   = (unsigned short*)alloc((size_t)Nn * IND * 2);
    unsigned short* hp_bf  = (unsigned short*)alloc((size_t)Nn * OUTD * 2);
    unsigned short* QKVwT  = (unsigned short*)alloc((size_t)3 * INTER * IND * 2);
    float*          qkvb   = (float*)alloc((size_t)3 * INTER * 4);
    unsigned short* RwT    = (unsigned short*)alloc((size_t)INTER * HID * 2);
    unsigned short* CwT    = (unsigned short*)alloc((size_t)OUTD * HID * 2);
    unsigned short* PwT    = (unsigned short*)alloc((size_t)2 * HID * OUTD * 2);
    unsigned short* QKVm   = (unsigned short*)alloc((size_t)Nn * 3 * INTER * 2);
    unsigned short* VTm    = (unsigned short*)alloc((size_t)Nn * INTER * 2);
    unsigned short* Sm     = (unsigned short*)alloc((size_t)Nn * Nn * 2);      // 134 MB scores
    float*          hret32 = (float*)alloc((size_t)4 * Nn * INTER * 4);        // K-split partials
    unsigned short* hretbf = (unsigned short*)alloc((size_t)Nn * INTER * 2);
    unsigned short* comb   = Sm;  // overlay: combined (8192x2048 bf16) over dead scores

    unsigned short* Qm = QKVm;
    unsigned short* Km = QKVm + INTER;
    unsigned short* Vm = QKVm + 2 * INTER;
    const int ldqkv = 3 * INTER;

    dim3 tb(32, 8);
    int n8 = Nn * IND / 8;
    cast2_kernel<<<dim3(n8 / 256, 2), 256, 0, stream>>>(h, hp, h_bf, hp_bf, n8);

    TD6 t6;
    t6.d[0] = {Qw, QKVwT,                          INTER, IND,     16, 16};
    t6.d[1] = {Kw, QKVwT + (size_t)INTER * IND,    INTER, IND,     16, 16};
    t6.d[2] = {Vw, QKVwT + (size_t)2 * INTER * IND,INTER, IND,     16, 16};
    t6.d[3] = {Rw, RwT,                            HID,   INTER,   32, 16};
    t6.d[4] = {Cw, CwT,                            HID,   OUTD,    32, 16};
    t6.d[5] = {Pw, PwT,                            OUTD,  2 * HID, 16, 64};
    multi_transpose_kernel<<<dim3(32, 64, 6), tb, 0, stream>>>(t6);
    concat_bias_kernel<<<6, 256, 0, stream>>>(Qb, Kb, Vb, qkvb);

    // fused QKV projection: (8192 x 1536) = h @ [Qw|Kw|Vw] + [Qb|Kb|Vb]
    gemm_bt_kernel<EP_BF16_BIAS><<<dim3(3 * INTER / 128, Nn / 128), 256, 0, stream>>>(
        h_bf, IND, QKVwT, IND, QKVm, ldqkv, IND, qkvb, nullptr, 0,
        nullptr, nullptr, nullptr, 0, nullptr, nullptr, nullptr);
    transpose_bf16_kernel<<<dim3(INTER / 32, Nn / 32), tb, 0, stream>>>(Vm, ldqkv, VTm, Nn);

    // stage2: scores = D .* (Q K^T), full 8192x8192 bf16
    gemm_bt_kernel<EP_BF16_DMUL><<<dim3(Nn / 128, Nn / 128), 256, 0, stream>>>(
        Qm, ldqkv, Km, ldqkv, Sm, Nn, INTER, nullptr, Dm, Nn,
        nullptr, nullptr, nullptr, 0, nullptr, nullptr, nullptr);

    // stage3: hret = scores @ V, K-split x4 into fp32 partials (z-grouped XCDs)
    gemm_bt_kernel<EP_F32><<<dim3(OUTD / 128, Nn / 128, 4), 256, 0, stream>>>(
        Sm, Nn, VTm, Nn, hret32, INTER, Nn / 4, nullptr, nullptr, 0,
        nullptr, nullptr, nullptr, (size_t)Nn * INTER, nullptr, nullptr, nullptr);
    sum4_cast_kernel<<<(Nn * INTER / 8) / 256, 256, 0, stream>>>(
        hret32, (size_t)Nn * INTER, hretbf, Nn * INTER / 8);

    // combined[:, :1024] = gelu(hret @ Rw + Rb) ; combined[:, 1024:] = h' @ Cw + Cb
    gemm_bt_kernel<EP_DUAL><<<dim3(2 * HID / 128, Nn / 128), 256, 0, stream>>>(
        hretbf, INTER, RwT, INTER, comb, 2 * HID, INTER, Rb, nullptr, 0,
        nullptr, nullptr, nullptr, 0, hp_bf, CwT, Cb);

    // x = combined @ Pw + Pb -> PReLU -> GroupNorm -> d_out (fp32)
    gemm_bt_kernel<EP_PRELU_GN><<<dim3(OUTD / 128, Nn / 128), 256, 0, stream>>>(
        comb, 2 * HID, PwT, 2 * HID, d_out, OUTD, 2 * HID, Pb, nullptr, 0,
        pa, gwt, gbt, 0, nullptr, nullptr, nullptr);
}

// Round 4
// 393.236 us; speedup vs baseline: 1.4303x; 1.0747x over previous
//
#include <hip/hip_runtime.h>
#include <math.h>

typedef __attribute__((ext_vector_type(8))) short bf16x8;
typedef __attribute__((ext_vector_type(4))) float f32x4;
typedef __attribute__((ext_vector_type(8))) unsigned short u16x8;

#define DEVFN __device__ __forceinline__
#define AS1 __attribute__((address_space(1)))
#define AS3 __attribute__((address_space(3)))

DEVFN unsigned short f2bf(float f) {
    unsigned int u = __float_as_uint(f);
    u += 0x7fffu + ((u >> 16) & 1u);   // RNE; inputs are finite
    return (unsigned short)(u >> 16);
}

// ---------------- dual cast f32 -> bf16 (h and h'), 8 elems/thread ----------------
__global__ void cast2_kernel(const float* __restrict__ a, const float* __restrict__ b,
                             unsigned short* __restrict__ oa, unsigned short* __restrict__ ob,
                             int n8) {
    const float* in = blockIdx.y ? b : a;
    unsigned short* out = blockIdx.y ? ob : oa;
    int i = blockIdx.x * blockDim.x + threadIdx.x;
    if (i >= n8) return;
    const float4* p = reinterpret_cast<const float4*>(in) + (size_t)i * 2;
    float4 x = p[0], y = p[1];
    u16x8 o;
    o[0] = f2bf(x.x); o[1] = f2bf(x.y); o[2] = f2bf(x.z); o[3] = f2bf(x.w);
    o[4] = f2bf(y.x); o[5] = f2bf(y.y); o[6] = f2bf(y.z); o[7] = f2bf(y.w);
    reinterpret_cast<u16x8*>(out)[i] = o;
}

// ---------------- sum 4 fp32 partials -> bf16 ----------------
__global__ void sum4_cast_kernel(const float* __restrict__ p, size_t stride,
                                 unsigned short* __restrict__ out, int n8) {
    int i = blockIdx.x * blockDim.x + threadIdx.x;
    if (i >= n8) return;
    const float4* a = reinterpret_cast<const float4*>(p) + (size_t)i * 2;
    const float4* b = reinterpret_cast<const float4*>(p + stride) + (size_t)i * 2;
    const float4* c = reinterpret_cast<const float4*>(p + 2 * stride) + (size_t)i * 2;
    const float4* d = reinterpret_cast<const float4*>(p + 3 * stride) + (size_t)i * 2;
    u16x8 o;
#pragma unroll
    for (int j = 0; j < 2; ++j) {
        float4 va = a[j], vb = b[j], vc = c[j], vd = d[j];
        o[4 * j + 0] = f2bf(va.x + vb.x + vc.x + vd.x);
        o[4 * j + 1] = f2bf(va.y + vb.y + vc.y + vd.y);
        o[4 * j + 2] = f2bf(va.z + vb.z + vc.z + vd.z);
        o[4 * j + 3] = f2bf(va.w + vb.w + vc.w + vd.w);
    }
    reinterpret_cast<u16x8*>(out)[i] = o;
}

// ---------------- concat 3 bias vectors (512 each) ----------------
__global__ void concat_bias_kernel(const float* __restrict__ a,
                                   const float* __restrict__ b,
                                   const float* __restrict__ c,
                                   float* __restrict__ o) {
    int i = blockIdx.x * blockDim.x + threadIdx.x;
    if (i >= 1536) return;
    o[i] = i < 512 ? a[i] : (i < 1024 ? b[i - 512] : c[i - 1024]);
}

// ---------------- fused multi-matrix transpose f32 -> bf16 ----------------
struct TD { const float* in; unsigned short* out; int ldin, ldout, nbx, nby; };
struct TD6 { TD d[6]; };

__global__ void multi_transpose_kernel(TD6 t6) {
    TD d = t6.d[blockIdx.z];
    if ((int)blockIdx.x >= d.nbx || (int)blockIdx.y >= d.nby) return;
    __shared__ unsigned short tile[32][34];
    int c0 = blockIdx.x * 32, r0 = blockIdx.y * 32;
    int tx = threadIdx.x, ty = threadIdx.y;  // (32,8)
#pragma unroll
    for (int i = 0; i < 32; i += 8)
        tile[ty + i][tx] = f2bf(d.in[(size_t)(r0 + ty + i) * d.ldin + c0 + tx]);
    __syncthreads();
#pragma unroll
    for (int i = 0; i < 32; i += 8)
        d.out[(size_t)(c0 + ty + i) * d.ldout + r0 + tx] = tile[tx][ty + i];
}

// ---------------- bf16 matrix transpose (for V) ----------------
__global__ void transpose_bf16_kernel(const unsigned short* __restrict__ in, int ldin,
                                      unsigned short* __restrict__ out, int ldout) {
    __shared__ unsigned short tile[32][34];
    int c0 = blockIdx.x * 32, r0 = blockIdx.y * 32;
    int tx = threadIdx.x, ty = threadIdx.y;
#pragma unroll
    for (int i = 0; i < 32; i += 8)
        tile[ty + i][tx] = in[(size_t)(r0 + ty + i) * ldin + c0 + tx];
    __syncthreads();
#pragma unroll
    for (int i = 0; i < 32; i += 8)
        out[(size_t)(c0 + ty + i) * ldout + r0 + tx] = tile[tx][ty + i];
}

// ================= 256x256 8-phase GEMM (T2+T3+T4+T5) =================
// C = A @ B^T. A:(M,K) bf16 lda, B:(N,K) bf16 ldb, K%64==0, M,N%256==0.
// 512 thr = 8 waves (2M x 4N); wave output 128x64 interleaved at 16-granularity:
// row(mi)=mi*32+wm*16, col(ni)=ni*64+wn*16. Per K-tile (BK=64): 4 phases
// {(mh0,nh0),(mh0,nh1),(mh1,nh1),(mh1,nh0)}, 16 MFMA each. Raw s_barrier
// (no drain); counted vmcnt(6) once per K-tile; stage stream lags 7 phases:
// group t stages [A1(t+1), A0(t+2), B0(t+2), B1(t+2)]. LDS 128 KiB.
enum { P8_DMUL = 0, P8_F32 = 1 };

#define DSREADA(BUF, MH)                                                        \
    {                                                                           \
        _Pragma("unroll") for (int q = 0; q < 4; ++q)                           \
        _Pragma("unroll") for (int kk = 0; kk < 2; ++kk) {                      \
            int row = ((MH) * 4 + q) * 32 + wm * 16 + (lane & 15);              \
            int ch = ((kk << 2) + (lane >> 4)) ^ (lane & 7);                    \
            areg[q][kk] = *(const bf16x8*)&As[BUF][row * 64 + ch * 8];          \
        }                                                                       \
    }

#define DSREADB(BUF, NH, BR)                                                    \
    {                                                                           \
        _Pragma("unroll") for (int p = 0; p < 2; ++p)                           \
        _Pragma("unroll") for (int kk = 0; kk < 2; ++kk) {                      \
            int row = ((NH) * 2 + p) * 64 + wn * 16 + (lane & 15);              \
            int ch = ((kk << 2) + (lane >> 4)) ^ (lane & 7);                    \
            BR[p][kk] = *(const bf16x8*)&Bs[BUF][row * 64 + ch * 8];            \
        }                                                                       \
    }

#define STAGEA(BUF, HALF, KT)                                                   \
    {                                                                           \
        const unsigned short* g0 = Ablk + (size_t)((HALF) * 128 + srow) * lda + (KT) * 64 + src8;       \
        const unsigned short* g1 = Ablk + (size_t)((HALF) * 128 + 64 + srow) * lda + (KT) * 64 + src8;  \
        unsigned short* d0 = &As[BUF][(HALF) * 8192 + (w * 64) * 8];            \
        unsigned short* d1 = &As[BUF][(HALF) * 8192 + (512 + w * 64) * 8];      \
        __builtin_amdgcn_global_load_lds((const AS1 void*)g0, (AS3 void*)d0, 16, 0, 0); \
        __builtin_amdgcn_global_load_lds((const AS1 void*)g1, (AS3 void*)d1, 16, 0, 0); \
    }

#define STAGEB(BUF, HALF, KT)                                                   \
    {                                                                           \
        const unsigned short* g0 = Bblk + (size_t)((HALF) * 128 + srow) * ldb + (KT) * 64 + src8;       \
        const unsigned short* g1 = Bblk + (size_t)((HALF) * 128 + 64 + srow) * ldb + (KT) * 64 + src8;  \
        unsigned short* d0 = &Bs[BUF][(HALF) * 8192 + (w * 64) * 8];            \
        unsigned short* d1 = &Bs[BUF][(HALF) * 8192 + (512 + w * 64) * 8];      \
        __builtin_amdgcn_global_load_lds((const AS1 void*)g0, (AS3 void*)d0, 16, 0, 0); \
        __builtin_amdgcn_global_load_lds((const AS1 void*)g1, (AS3 void*)d1, 16, 0, 0); \
    }

#define MMAC(BR, MB, NB)                                                        \
    {                                                                           \
        __builtin_amdgcn_s_setprio(1);                                          \
        _Pragma("unroll") for (int q = 0; q < 4; ++q)                           \
        _Pragma("unroll") for (int p = 0; p < 2; ++p)                           \
        _Pragma("unroll") for (int kk = 0; kk < 2; ++kk)                        \
            acc[(MB) + q][(NB) + p] = __builtin_amdgcn_mfma_f32_16x16x32_bf16(  \
                areg[q][kk], BR[p][kk], acc[(MB) + q][(NB) + p], 0, 0, 0);      \
        __builtin_amdgcn_s_setprio(0);                                          \
    }

#define VMCNT6 asm volatile("s_waitcnt vmcnt(6)" ::: "memory")
#define VMCNT0 asm volatile("s_waitcnt vmcnt(0)" ::: "memory")
#define BAR __builtin_amdgcn_s_barrier()

template <int MODE>
__global__ __launch_bounds__(512, 2) void gemm8p_kernel(
    const unsigned short* __restrict__ A, int lda,
    const unsigned short* __restrict__ B, int ldb,
    void* __restrict__ Cv, int ldc, int K,
    const float* __restrict__ Dmul, int ldd, size_t zstride) {
    __shared__ alignas(16) unsigned short As[2][256 * 64];
    __shared__ alignas(16) unsigned short Bs[2][256 * 64];

    unsigned bx, by, zi = 0;
    if (MODE == P8_F32) {
        // z-grouped XCD mapping: z-chunk -> XCD pair; V z-slab (2MB) stays L2-hot
        unsigned gx = gridDim.x;
        unsigned L = (blockIdx.z * gridDim.y + blockIdx.y) * gx + blockIdx.x;
        unsigned xcd = L & 7u, slot = L >> 3;
        zi = xcd >> 1;
        unsigned t = slot * 2 + (xcd & 1u);
        bx = t & (gx - 1);
        by = t / gx;
    } else {
        unsigned nwg = gridDim.x * gridDim.y;
        unsigned bid = blockIdx.y * gridDim.x + blockIdx.x;
        unsigned cpx = nwg >> 3;
        bid = (bid & 7u) * cpx + (bid >> 3);
        bx = bid % gridDim.x;
        by = bid / gridDim.x;
    }
    size_t m0 = (size_t)by * 256, n0 = (size_t)bx * 256;

    int tid = threadIdx.x;
    int lane = tid & 63, w = tid >> 6;
    int wm = w >> 2, wn = w & 3;

    const unsigned short* Ablk = A + m0 * lda + (size_t)zi * K;
    const unsigned short* Bblk = B + n0 * ldb + (size_t)zi * K;
    int src8 = ((lane & 7) ^ (lane >> 3)) * 8;  // pre-swizzled source col (elems)
    int srow = w * 8 + (lane >> 3);             // staging row within 64-row slab

    f32x4 acc[8][4];
#pragma unroll
    for (int i = 0; i < 8; ++i)
#pragma unroll
        for (int j = 0; j < 4; ++j)
#pragma unroll
            for (int r = 0; r < 4; ++r) acc[i][j][r] = 0.f;

    const int NT = K >> 6;

    // prologue: stage tile0 fully + 3 halves of tile1; wait tile0
    STAGEA(0, 0, 0); STAGEB(0, 0, 0); STAGEB(0, 1, 0); STAGEA(0, 1, 0);
    if (NT > 1) { STAGEA(1, 0, 1); STAGEB(1, 0, 1); STAGEB(1, 1, 1); }
    if (NT > 1) { VMCNT6; } else { VMCNT0; }
    BAR;

    bf16x8 areg[4][2], breg0[2][2], breg1[2][2];

    for (int t = 0; t < NT; ++t) {
        int buf = t & 1;
        // phase 1: quadrant (mh0, nh0)
        DSREADA(buf, 0);
        DSREADB(buf, 0, breg0);
        if (t + 1 < NT) STAGEA(buf ^ 1, 1, t + 1);
        BAR;
        MMAC(breg0, 0, 0);
        BAR;
        // phase 2: (mh0, nh1)
        DSREADB(buf, 1, breg1);
        if (t + 2 < NT) STAGEA(buf, 0, t + 2);
        BAR;
        MMAC(breg1, 0, 2);
        BAR;
        // phase 3: (mh1, nh1)
        DSREADA(buf, 1);
        if (t + 2 < NT) STAGEB(buf, 0, t + 2);
        BAR;
        MMAC(breg1, 4, 2);
        BAR;
        // phase 4: (mh1, nh0) + K-tile checkpoint
        if (t + 2 < NT) { STAGEB(buf, 1, t + 2); VMCNT6; } else { VMCNT0; }
        BAR;
        MMAC(breg0, 4, 0);
        BAR;
    }

    // epilogue: C/D frag layout col=lane&15, row=(lane>>4)*4+r  [m89-verified]
#pragma unroll
    for (int mi = 0; mi < 8; ++mi) {
#pragma unroll
        for (int ni = 0; ni < 4; ++ni) {
            size_t gcol = n0 + ni * 64 + wn * 16 + (lane & 15);
#pragma unroll
            for (int r = 0; r < 4; ++r) {
                size_t grow = m0 + mi * 32 + wm * 16 + ((lane >> 4) << 2) + r;
                if (MODE == P8_DMUL) {
                    float v = acc[mi][ni][r] * Dmul[grow * (size_t)ldd + gcol];
                    ((unsigned short*)Cv)[grow * (size_t)ldc + gcol] = f2bf(v);
                } else {
                    float* Cf = (float*)Cv + zi * zstride;
                    Cf[grow * (size_t)ldc + gcol] = acc[mi][ni][r];
                }
            }
        }
    }
}

// ---------------- 128x128 GEMM (2 blocks/CU) for small-N stages ----------------
enum { EP_BF16_BIAS = 0, EP_PRELU_GN = 4, EP_DUAL = 5 };

template <int MODE>
__global__ __launch_bounds__(256, 2) void gemm_bt_kernel(
    const unsigned short* __restrict__ A, int lda,
    const unsigned short* __restrict__ B, int ldb,
    void* __restrict__ Cv, int ldc, int K,
    const float* __restrict__ bias,
    const float* __restrict__ PA, const float* __restrict__ GW,
    const float* __restrict__ GB,
    const unsigned short* __restrict__ A2,
    const unsigned short* __restrict__ B2,
    const float* __restrict__ bias2) {
    __shared__ alignas(16) unsigned short As[2][128 * 64];
    __shared__ alignas(16) unsigned short Bs[2][128 * 64];

    unsigned nwg = gridDim.x * gridDim.y;
    unsigned bid = blockIdx.y * gridDim.x + blockIdx.x;
    unsigned cpx = nwg >> 3;
    bid = (bid & 7u) * cpx + (bid >> 3);
    unsigned bx = bid % gridDim.x, by = bid / gridDim.x;
    size_t m0 = (size_t)by * 128;
    size_t nB = (size_t)bx * 128;
    size_t ncol0 = nB;

    const unsigned short* Ause = A;
    const unsigned short* Buse = B;
    const float* bias_use = bias;
    bool apply_gelu = false;
    if (MODE == EP_DUAL) {
        unsigned half = gridDim.x >> 1;
        if (bx >= half) {  // C-branch: h' @ Cw + Cb -> cols 1024..2047
            nB = (size_t)(bx - half) * 128;
            ncol0 = 1024 + nB;
            Ause = A2; Buse = B2; bias_use = bias2;
        } else {
            apply_gelu = true;
        }
    }

    int tid = threadIdx.x;
    int lane = tid & 63, w = tid >> 6;
    int wr = w >> 1, wc = w & 1;
    int cif = lane & 15;
    int rif = (lane >> 4) << 2;

    f32x4 acc[4][4];
#pragma unroll
    for (int i = 0; i < 4; ++i)
#pragma unroll
        for (int j = 0; j < 4; ++j)
#pragma unroll
            for (int r = 0; r < 4; ++r) acc[i][j][r] = 0.f;

    const unsigned short* Ablk = Ause + m0 * lda;
    const unsigned short* Bblk = Buse + nB * ldb;
    int srccol = ((lane & 7) ^ (lane >> 3)) * 8;
    int srow = w * 32 + (lane >> 3);
    int nkt = K >> 6;

    auto stage = [&](int buf, int kt) {
        int k0 = kt << 6;
        unsigned short* la = &As[buf][w * 2048];
        unsigned short* lb = &Bs[buf][w * 2048];
#pragma unroll
        for (int i = 0; i < 4; ++i) {
            __builtin_amdgcn_global_load_lds(
                (const AS1 void*)(Ablk + (size_t)(srow + i * 8) * lda + k0 + srccol),
                (AS3 void*)(la + i * 512), 16, 0, 0);
            __builtin_amdgcn_global_load_lds(
                (const AS1 void*)(Bblk + (size_t)(srow + i * 8) * ldb + k0 + srccol),
                (AS3 void*)(lb + i * 512), 16, 0, 0);
        }
    };

    stage(0, 0);
    __syncthreads();

    for (int kt = 0; kt < nkt; ++kt) {
        int cur = kt & 1;
        if (kt + 1 < nkt) stage(cur ^ 1, kt + 1);

        const bf16x8* Ap = reinterpret_cast<const bf16x8*>(As[cur]);
        const bf16x8* Bp = reinterpret_cast<const bf16x8*>(Bs[cur]);
#pragma unroll
        for (int kk = 0; kk < 2; ++kk) {
            bf16x8 af[4], bfr[4];
#pragma unroll
            for (int mi = 0; mi < 4; ++mi) {
                int row = wr * 64 + mi * 16 + (lane & 15);
                int slot = ((kk << 2) + (lane >> 4)) ^ (row & 7);
                af[mi] = Ap[row * 8 + slot];
            }
#pragma unroll
            for (int ni = 0; ni < 4; ++ni) {
                int row = wc * 64 + ni * 16 + (lane & 15);
                int slot = ((kk << 2) + (lane >> 4)) ^ (row & 7);
                bfr[ni] = Bp[row * 8 + slot];
            }
#pragma unroll
            for (int mi = 0; mi < 4; ++mi)
#pragma unroll
                for (int ni = 0; ni < 4; ++ni)
                    acc[mi][ni] = __builtin_amdgcn_mfma_f32_16x16x32_bf16(
                        af[mi], bfr[ni], acc[mi][ni], 0, 0, 0);
        }
        __syncthreads();
    }

    if (MODE == EP_PRELU_GN) {
        float* Cf = (float*)Cv;
        float pbv[4], pav[4], gwv[4], gbv[4];
        size_t gcolv[4];
#pragma unroll
        for (int ni = 0; ni < 4; ++ni) {
            gcolv[ni] = ncol0 + wc * 64 + ni * 16 + cif;
            pbv[ni] = bias[gcolv[ni]];
            pav[ni] = PA[gcolv[ni]];
            gwv[ni] = GW[gcolv[ni]];
            gbv[ni] = GB[gcolv[ni]];
        }
#pragma unroll
        for (int mi = 0; mi < 4; ++mi) {
#pragma unroll
            for (int ni = 0; ni < 4; ++ni)
#pragma unroll
                for (int r = 0; r < 4; ++r) {
                    float v = acc[mi][ni][r] + pbv[ni];
                    acc[mi][ni][r] = v >= 0.f ? v : pav[ni] * v;
                }
#pragma unroll
            for (int p = 0; p < 2; ++p) {
                float s[4], ss[4];
#pragma unroll
                for (int r = 0; r < 4; ++r) {
                    float a0 = acc[mi][2 * p][r], a1 = acc[mi][2 * p + 1][r];
                    s[r] = a0 + a1;
                    ss[r] = a0 * a0 + a1 * a1;
                }
#pragma unroll
                for (int msk = 1; msk < 16; msk <<= 1)
#pragma unroll
                    for (int r = 0; r < 4; ++r) {
                        s[r] += __shfl_xor(s[r], msk);
                        ss[r] += __shfl_xor(ss[r], msk);
                    }
#pragma unroll
                for (int r = 0; r < 4; ++r) {
                    float mu = s[r] * (1.f / 32.f);
                    float inv = rsqrtf(ss[r] * (1.f / 32.f) - mu * mu + 1e-5f);
                    size_t grow = m0 + wr * 64 + mi * 16 + rif + r;
#pragma unroll
                    for (int q = 0; q < 2; ++q) {
                        int ni = 2 * p + q;
                        Cf[grow * (size_t)ldc + gcolv[ni]] =
                            (acc[mi][ni][r] - mu) * inv * gwv[ni] + gbv[ni];
                    }
                }
            }
        }
        return;
    }

#pragma unroll
    for (int mi = 0; mi < 4; ++mi) {
#pragma unroll
        for (int ni = 0; ni < 4; ++ni) {
            size_t gcol = ncol0 + wc * 64 + ni * 16 + cif;
            size_t bcol = nB + wc * 64 + ni * 16 + cif;
            float bval = bias_use ? bias_use[bcol] : 0.f;
#pragma unroll
            for (int r = 0; r < 4; ++r) {
                size_t grow = m0 + wr * 64 + mi * 16 + rif + r;
                float val = acc[mi][ni][r] + bval;
                if (MODE == EP_DUAL && apply_gelu)
                    val = 0.5f * val * (1.f + erff(val * 0.70710678118654752f));
                ((unsigned short*)Cv)[grow * (size_t)ldc + gcol] = f2bf(val);
            }
        }
    }
}

extern "C" void kernel_launch(void* const* d_in, const int* in_sizes, int n_in,
                              void* d_out, int out_size, void* d_ws, size_t ws_size,
                              hipStream_t stream) {
    constexpr int Nn = 8192, IND = 512, INTER = 512, HID = 1024, OUTD = 512;
    const float* h   = (const float*)d_in[0];
    const float* Dm  = (const float*)d_in[1];
    const float* hp  = (const float*)d_in[2];
    const float* Qw  = (const float*)d_in[3];
    const float* Qb  = (const float*)d_in[4];
    const float* Kw  = (const float*)d_in[5];
    const float* Kb  = (const float*)d_in[6];
    const float* Vw  = (const float*)d_in[7];
    const float* Vb  = (const float*)d_in[8];
    const float* Rw  = (const float*)d_in[9];
    const float* Rb  = (const float*)d_in[10];
    const float* Cw  = (const float*)d_in[11];
    const float* Cb  = (const float*)d_in[12];
    const float* Pw  = (const float*)d_in[13];
    const float* Pb  = (const float*)d_in[14];
    const float* pa  = (const float*)d_in[15];
    const float* gwt = (const float*)d_in[16];
    const float* gbt = (const float*)d_in[17];
    (void)in_sizes; (void)n_in; (void)out_size; (void)ws_size;

    char* ws = (char*)d_ws;
    size_t cur = 0;
    auto alloc = [&](size_t bytes) -> void* {
        void* p = ws + cur;
        cur += (bytes + 255) & ~(size_t)255;
        return p;
    };
    unsigned short* h_bf   = (unsigned short*)alloc((size_t)Nn * IND * 2);
    unsigned short* hp_bf  = (unsigned short*)alloc((size_t)Nn * OUTD * 2);
    unsigned short* QKVwT  = (unsigned short*)alloc((size_t)3 * INTER * IND * 2);
    float*          qkvb   = (float*)alloc((size_t)3 * INTER * 4);
    unsigned short* RwT    = (unsigned short*)alloc((size_t)INTER * HID * 2);
    unsigned short* CwT    = (unsigned short*)alloc((size_t)OUTD * HID * 2);
    unsigned short* PwT    = (unsigned short*)alloc((size_t)2 * HID * OUTD * 2);
    unsigned short* QKVm   = (unsigned short*)alloc((size_t)Nn * 3 * INTER * 2);
    unsigned short* VTm    = (unsigned short*)alloc((size_t)Nn * INTER * 2);
    unsigned short* Sm     = (unsigned short*)alloc((size_t)Nn * Nn * 2);      // 134 MB scores
    float*          hret32 = (float*)alloc((size_t)4 * Nn * INTER * 4);        // K-split partials
    unsigned short* hretbf = (unsigned short*)alloc((size_t)Nn * INTER * 2);
    unsigned short* comb   = Sm;  // overlay: combined (8192x2048 bf16) over dead scores

    unsigned short* Qm = QKVm;
    unsigned short* Km = QKVm + INTER;
    unsigned short* Vm = QKVm + 2 * INTER;
    const int ldqkv = 3 * INTER;

    dim3 tb(32, 8);
    int n8 = Nn * IND / 8;
    cast2_kernel<<<dim3(n8 / 256, 2), 256, 0, stream>>>(h, hp, h_bf, hp_bf, n8);

    TD6 t6;
    t6.d[0] = {Qw, QKVwT,                          INTER, IND,     16, 16};
    t6.d[1] = {Kw, QKVwT + (size_t)INTER * IND,    INTER, IND,     16, 16};
    t6.d[2] = {Vw, QKVwT + (size_t)2 * INTER * IND,INTER, IND,     16, 16};
    t6.d[3] = {Rw, RwT,                            HID,   INTER,   32, 16};
    t6.d[4] = {Cw, CwT,                            HID,   OUTD,    32, 16};
    t6.d[5] = {Pw, PwT,                            OUTD,  2 * HID, 16, 64};
    multi_transpose_kernel<<<dim3(32, 64, 6), tb, 0, stream>>>(t6);
    concat_bias_kernel<<<6, 256, 0, stream>>>(Qb, Kb, Vb, qkvb);

    // fused QKV projection: (8192 x 1536) = h @ [Qw|Kw|Vw] + [Qb|Kb|Vb]
    gemm_bt_kernel<EP_BF16_BIAS><<<dim3(3 * INTER / 128, Nn / 128), 256, 0, stream>>>(
        h_bf, IND, QKVwT, IND, QKVm, ldqkv, IND, qkvb,
        nullptr, nullptr, nullptr, nullptr, nullptr, nullptr);
    transpose_bf16_kernel<<<dim3(INTER / 32, Nn / 32), tb, 0, stream>>>(Vm, ldqkv, VTm, Nn);

    // stage2: scores = D .* (Q K^T), full 8192x8192 bf16  [8-phase 256^2]
    gemm8p_kernel<P8_DMUL><<<dim3(Nn / 256, Nn / 256), 512, 0, stream>>>(
        Qm, ldqkv, Km, ldqkv, Sm, Nn, INTER, Dm, Nn, 0);

    // stage3: hret = scores @ V, K-split x4 into fp32 partials  [8-phase 256^2]
    gemm8p_kernel<P8_F32><<<dim3(OUTD / 256, Nn / 256, 4), 512, 0, stream>>>(
        Sm, Nn, VTm, Nn, hret32, INTER, Nn / 4, nullptr, 0, (size_t)Nn * INTER);
    sum4_cast_kernel<<<(Nn * INTER / 8) / 256, 256, 0, stream>>>(
        hret32, (size_t)Nn * INTER, hretbf, Nn * INTER / 8);

    // combined[:, :1024] = gelu(hret @ Rw + Rb) ; combined[:, 1024:] = h' @ Cw + Cb
    gemm_bt_kernel<EP_DUAL><<<dim3(2 * HID / 128, Nn / 128), 256, 0, stream>>>(
        hretbf, INTER, RwT, INTER, comb, 2 * HID, INTER, Rb,
        nullptr, nullptr, nullptr, hp_bf, CwT, Cb);

    // x = combined @ Pw + Pb -> PReLU -> GroupNorm -> d_out (fp32)
    gemm_bt_kernel<EP_PRELU_GN><<<dim3(OUTD / 128, Nn / 128), 256, 0, stream>>>(
        comb, 2 * HID, PwT, 2 * HID, d_out, OUTD, 2 * HID, Pb,
        pa, gwt, gbt, nullptr, nullptr, nullptr);
}

// Round 5
// 378.125 us; speedup vs baseline: 1.4874x; 1.0400x over previous
//
#include <hip/hip_runtime.h>
#include <math.h>

typedef __attribute__((ext_vector_type(8))) short bf16x8;
typedef __attribute__((ext_vector_type(4))) float f32x4;
typedef __attribute__((ext_vector_type(8))) unsigned short u16x8;

#define DEVFN __device__ __forceinline__
#define AS1 __attribute__((address_space(1)))
#define AS3 __attribute__((address_space(3)))

DEVFN unsigned short f2bf(float f) {
    unsigned int u = __float_as_uint(f);
    u += 0x7fffu + ((u >> 16) & 1u);   // RNE; inputs are finite
    return (unsigned short)(u >> 16);
}

// ---------------- dual cast f32 -> bf16 (h and h'), 8 elems/thread ----------------
__global__ void cast2_kernel(const float* __restrict__ a, const float* __restrict__ b,
                             unsigned short* __restrict__ oa, unsigned short* __restrict__ ob,
                             int n8) {
    const float* in = blockIdx.y ? b : a;
    unsigned short* out = blockIdx.y ? ob : oa;
    int i = blockIdx.x * blockDim.x + threadIdx.x;
    if (i >= n8) return;
    const float4* p = reinterpret_cast<const float4*>(in) + (size_t)i * 2;
    float4 x = p[0], y = p[1];
    u16x8 o;
    o[0] = f2bf(x.x); o[1] = f2bf(x.y); o[2] = f2bf(x.z); o[3] = f2bf(x.w);
    o[4] = f2bf(y.x); o[5] = f2bf(y.y); o[6] = f2bf(y.z); o[7] = f2bf(y.w);
    reinterpret_cast<u16x8*>(out)[i] = o;
}

// ---------------- sum 4 fp32 partials -> bf16 ----------------
__global__ void sum4_cast_kernel(const float* __restrict__ p, size_t stride,
                                 unsigned short* __restrict__ out, int n8) {
    int i = blockIdx.x * blockDim.x + threadIdx.x;
    if (i >= n8) return;
    const float4* a = reinterpret_cast<const float4*>(p) + (size_t)i * 2;
    const float4* b = reinterpret_cast<const float4*>(p + stride) + (size_t)i * 2;
    const float4* c = reinterpret_cast<const float4*>(p + 2 * stride) + (size_t)i * 2;
    const float4* d = reinterpret_cast<const float4*>(p + 3 * stride) + (size_t)i * 2;
    u16x8 o;
#pragma unroll
    for (int j = 0; j < 2; ++j) {
        float4 va = a[j], vb = b[j], vc = c[j], vd = d[j];
        o[4 * j + 0] = f2bf(va.x + vb.x + vc.x + vd.x);
        o[4 * j + 1] = f2bf(va.y + vb.y + vc.y + vd.y);
        o[4 * j + 2] = f2bf(va.z + vb.z + vc.z + vd.z);
        o[4 * j + 3] = f2bf(va.w + vb.w + vc.w + vd.w);
    }
    reinterpret_cast<u16x8*>(out)[i] = o;
}

// ---------------- concat 3 bias vectors (512 each) ----------------
__global__ void concat_bias_kernel(const float* __restrict__ a,
                                   const float* __restrict__ b,
                                   const float* __restrict__ c,
                                   float* __restrict__ o) {
    int i = blockIdx.x * blockDim.x + threadIdx.x;
    if (i >= 1536) return;
    o[i] = i < 512 ? a[i] : (i < 1024 ? b[i - 512] : c[i - 1024]);
}

// ---------------- fused multi-matrix transpose f32 -> bf16 ----------------
struct TD { const float* in; unsigned short* out; int ldin, ldout, nbx, nby; };
struct TD6 { TD d[6]; };

__global__ void multi_transpose_kernel(TD6 t6) {
    TD d = t6.d[blockIdx.z];
    if ((int)blockIdx.x >= d.nbx || (int)blockIdx.y >= d.nby) return;
    __shared__ unsigned short tile[32][34];
    int c0 = blockIdx.x * 32, r0 = blockIdx.y * 32;
    int tx = threadIdx.x, ty = threadIdx.y;  // (32,8)
#pragma unroll
    for (int i = 0; i < 32; i += 8)
        tile[ty + i][tx] = f2bf(d.in[(size_t)(r0 + ty + i) * d.ldin + c0 + tx]);
    __syncthreads();
#pragma unroll
    for (int i = 0; i < 32; i += 8)
        d.out[(size_t)(c0 + ty + i) * d.ldout + r0 + tx] = tile[tx][ty + i];
}

// ---------------- bf16 matrix transpose (for V) ----------------
__global__ void transpose_bf16_kernel(const unsigned short* __restrict__ in, int ldin,
                                      unsigned short* __restrict__ out, int ldout) {
    __shared__ unsigned short tile[32][34];
    int c0 = blockIdx.x * 32, r0 = blockIdx.y * 32;
    int tx = threadIdx.x, ty = threadIdx.y;
#pragma unroll
    for (int i = 0; i < 32; i += 8)
        tile[ty + i][tx] = in[(size_t)(r0 + ty + i) * ldin + c0 + tx];
    __syncthreads();
#pragma unroll
    for (int i = 0; i < 32; i += 8)
        out[(size_t)(c0 + ty + i) * ldout + r0 + tx] = tile[tx][ty + i];
}

// ================= 256x256 8-phase GEMM (T2+T3+T4+T5) =================
// C = A @ B^T. A:(M,K) bf16 lda, B:(N,K) bf16 ldb, K%64==0, M,N%256==0.
// 512 thr = 8 waves (2M x 4N); wave output 128x64 interleaved at 16-granularity.
// LDS reads are INLINE-ASM ds_read_b128 (invisible to alias analysis, so the
// compiler cannot emit conservative vmcnt(0) against the LDS-DMA stream);
// waits are fully manual: vmcnt(6) once/K-tile, lgkmcnt(0)+sched_barrier(0)
// per phase (rule #18), raw s_barrier (no drain).
enum { P8_DMUL = 0, P8_F32 = 1 };

#define DSR(dst, base, IMM) \
    asm volatile("ds_read_b128 %0, %1 offset:%c2" : "=v"(dst) : "v"(base), "i"(IMM))

// A subtile: rows MH*128 + q*32 + (wm*16+lrow); 8 reads
#define DSA(MHOFF)                                \
    DSR(areg[0][0], abase0, (MHOFF) + 0 * 4096);  \
    DSR(areg[0][1], abase1, (MHOFF) + 0 * 4096);  \
    DSR(areg[1][0], abase0, (MHOFF) + 1 * 4096);  \
    DSR(areg[1][1], abase1, (MHOFF) + 1 * 4096);  \
    DSR(areg[2][0], abase0, (MHOFF) + 2 * 4096);  \
    DSR(areg[2][1], abase1, (MHOFF) + 2 * 4096);  \
    DSR(areg[3][0], abase0, (MHOFF) + 3 * 4096);  \
    DSR(areg[3][1], abase1, (MHOFF) + 3 * 4096);

// B subtile: rows NH*128 + p*64 + (wn*16+lrow); 4 reads
#define DSB(BR, NHOFF)                            \
    DSR(BR[0][0], bbase0, (NHOFF) + 0 * 8192);    \
    DSR(BR[0][1], bbase1, (NHOFF) + 0 * 8192);    \
    DSR(BR[1][0], bbase0, (NHOFF) + 1 * 8192);    \
    DSR(BR[1][1], bbase1, (NHOFF) + 1 * 8192);

#define STAGEA(BUF, HALF, KT)                                                   \
    {                                                                           \
        const unsigned short* g0 = Ablk + (size_t)((HALF) * 128 + srow) * lda + (KT) * 64 + src8;       \
        const unsigned short* g1 = Ablk + (size_t)((HALF) * 128 + 64 + srow) * lda + (KT) * 64 + src8;  \
        unsigned short* d0 = &As[BUF][(HALF) * 8192 + (w * 64) * 8];            \
        unsigned short* d1 = &As[BUF][(HALF) * 8192 + (512 + w * 64) * 8];      \
        __builtin_amdgcn_global_load_lds((const AS1 void*)g0, (AS3 void*)d0, 16, 0, 0); \
        __builtin_amdgcn_global_load_lds((const AS1 void*)g1, (AS3 void*)d1, 16, 0, 0); \
    }

#define STAGEB(BUF, HALF, KT)                                                   \
    {                                                                           \
        const unsigned short* g0 = Bblk + (size_t)((HALF) * 128 + srow) * ldb + (KT) * 64 + src8;       \
        const unsigned short* g1 = Bblk + (size_t)((HALF) * 128 + 64 + srow) * ldb + (KT) * 64 + src8;  \
        unsigned short* d0 = &Bs[BUF][(HALF) * 8192 + (w * 64) * 8];            \
        unsigned short* d1 = &Bs[BUF][(HALF) * 8192 + (512 + w * 64) * 8];      \
        __builtin_amdgcn_global_load_lds((const AS1 void*)g0, (AS3 void*)d0, 16, 0, 0); \
        __builtin_amdgcn_global_load_lds((const AS1 void*)g1, (AS3 void*)d1, 16, 0, 0); \
    }

#define MMAC(BR, MB, NB)                                                        \
    {                                                                           \
        __builtin_amdgcn_s_setprio(1);                                          \
        _Pragma("unroll") for (int q = 0; q < 4; ++q)                           \
        _Pragma("unroll") for (int p = 0; p < 2; ++p)                           \
        _Pragma("unroll") for (int kk = 0; kk < 2; ++kk)                        \
            acc[(MB) + q][(NB) + p] = __builtin_amdgcn_mfma_f32_16x16x32_bf16(  \
                areg[q][kk], BR[p][kk], acc[(MB) + q][(NB) + p], 0, 0, 0);      \
        __builtin_amdgcn_s_setprio(0);                                          \
    }

#define VMCNT6 asm volatile("s_waitcnt vmcnt(6)" ::: "memory")
#define VMCNT0 asm volatile("s_waitcnt vmcnt(0)" ::: "memory")
#define BAR __builtin_amdgcn_s_barrier()
#define WAITDS                                          \
    asm volatile("s_waitcnt lgkmcnt(0)" ::: "memory");  \
    __builtin_amdgcn_sched_barrier(0)

template <int MODE>
__global__ __launch_bounds__(512, 2) void gemm8p_kernel(
    const unsigned short* __restrict__ A, int lda,
    const unsigned short* __restrict__ B, int ldb,
    void* __restrict__ Cv, int ldc, int K,
    const float* __restrict__ Dmul, int ldd, size_t zstride) {
    __shared__ alignas(16) unsigned short As[2][256 * 64];
    __shared__ alignas(16) unsigned short Bs[2][256 * 64];

    unsigned bx, by, zi = 0;
    if (MODE == P8_F32) {
        // z-grouped XCD mapping: z-chunk -> XCD pair; V z-slab (2MB) stays L2-hot
        unsigned gx = gridDim.x;
        unsigned L = (blockIdx.z * gridDim.y + blockIdx.y) * gx + blockIdx.x;
        unsigned xcd = L & 7u, slot = L >> 3;
        zi = xcd >> 1;
        unsigned t = slot * 2 + (xcd & 1u);
        bx = t & (gx - 1);
        by = t / gx;
    } else {
        unsigned nwg = gridDim.x * gridDim.y;
        unsigned bid = blockIdx.y * gridDim.x + blockIdx.x;
        unsigned cpx = nwg >> 3;
        bid = (bid & 7u) * cpx + (bid >> 3);
        bx = bid % gridDim.x;
        by = bid / gridDim.x;
    }
    size_t m0 = (size_t)by * 256, n0 = (size_t)bx * 256;

    int tid = threadIdx.x;
    int lane = tid & 63, w = tid >> 6;
    int wm = w >> 2, wn = w & 3;
    int lrow = lane & 15;

    const unsigned short* Ablk = A + m0 * lda + (size_t)zi * K;
    const unsigned short* Bblk = B + n0 * ldb + (size_t)zi * K;
    int src8 = ((lane & 7) ^ (lane >> 3)) * 8;  // pre-swizzled source col (elems)
    int srow = w * 8 + (lane >> 3);             // staging row within 64-row slab

    // LDS byte addresses for asm ds_read: row stride 128B, chunk 16B,
    // chunk index = ((kk<<2) + (lane>>4)) ^ (lane&7)  [matches staging swizzle]
    unsigned asBase = (unsigned)(uintptr_t)(AS3 const void*)&As[0][0];
    unsigned bsBase = (unsigned)(uintptr_t)(AS3 const void*)&Bs[0][0];
    unsigned cA0 = (unsigned)((((lane >> 4)) ^ (lane & 7)) * 16);
    unsigned cA1 = (unsigned)(((4 + (lane >> 4)) ^ (lane & 7)) * 16);
    unsigned aOff0 = asBase + (unsigned)((wm * 16 + lrow) * 128);
    unsigned bOff0 = bsBase + (unsigned)((wn * 16 + lrow) * 128);

    f32x4 acc[8][4];
#pragma unroll
    for (int i = 0; i < 8; ++i)
#pragma unroll
        for (int j = 0; j < 4; ++j)
#pragma unroll
            for (int r = 0; r < 4; ++r) acc[i][j][r] = 0.f;

    const int NT = K >> 6;

    // prologue: stage tile0 fully + 3 halves of tile1; wait tile0
    STAGEA(0, 0, 0); STAGEB(0, 0, 0); STAGEB(0, 1, 0); STAGEA(0, 1, 0);
    if (NT > 1) { STAGEA(1, 0, 1); STAGEB(1, 0, 1); STAGEB(1, 1, 1); }
    if (NT > 1) { VMCNT6; } else { VMCNT0; }
    BAR;

    bf16x8 areg[4][2], breg0[2][2], breg1[2][2];

    for (int t = 0; t < NT; ++t) {
        int buf = t & 1;
        unsigned boff = (unsigned)buf * 32768u;
        unsigned abase0 = aOff0 + boff + cA0;
        unsigned abase1 = aOff0 + boff + cA1;
        unsigned bbase0 = bOff0 + boff + cA0;
        unsigned bbase1 = bOff0 + boff + cA1;

        // phase 1: quadrant (mh0, nh0)
        DSA(0);
        DSB(breg0, 0);
        if (t + 1 < NT) STAGEA(buf ^ 1, 1, t + 1);
        BAR;
        WAITDS;
        MMAC(breg0, 0, 0);
        BAR;
        // phase 2: (mh0, nh1)
        DSB(breg1, 16384);
        if (t + 2 < NT) STAGEA(buf, 0, t + 2);
        BAR;
        WAITDS;
        MMAC(breg1, 0, 2);
        BAR;
        // phase 3: (mh1, nh1)
        DSA(16384);
        if (t + 2 < NT) STAGEB(buf, 0, t + 2);
        BAR;
        WAITDS;
        MMAC(breg1, 4, 2);
        BAR;
        // phase 4: (mh1, nh0) + K-tile checkpoint (no new ds_reads)
        if (t + 2 < NT) { STAGEB(buf, 1, t + 2); VMCNT6; } else { VMCNT0; }
        BAR;
        MMAC(breg0, 4, 0);
        BAR;
    }

    // epilogue: C/D frag layout col=lane&15, row=(lane>>4)*4+r  [m89-verified]
#pragma unroll
    for (int mi = 0; mi < 8; ++mi) {
#pragma unroll
        for (int ni = 0; ni < 4; ++ni) {
            size_t gcol = n0 + ni * 64 + wn * 16 + (lane & 15);
#pragma unroll
            for (int r = 0; r < 4; ++r) {
                size_t grow = m0 + mi * 32 + wm * 16 + ((lane >> 4) << 2) + r;
                if (MODE == P8_DMUL) {
                    float v = acc[mi][ni][r] * Dmul[grow * (size_t)ldd + gcol];
                    ((unsigned short*)Cv)[grow * (size_t)ldc + gcol] = f2bf(v);
                } else {
                    float* Cf = (float*)Cv + zi * zstride;
                    Cf[grow * (size_t)ldc + gcol] = acc[mi][ni][r];
                }
            }
        }
    }
}

// ---------------- 128x128 GEMM (2 blocks/CU) for small-N stages ----------------
enum { EP_BF16_BIAS = 0, EP_PRELU_GN = 4, EP_DUAL = 5 };

template <int MODE>
__global__ __launch_bounds__(256, 2) void gemm_bt_kernel(
    const unsigned short* __restrict__ A, int lda,
    const unsigned short* __restrict__ B, int ldb,
    void* __restrict__ Cv, int ldc, int K,
    const float* __restrict__ bias,
    const float* __restrict__ PA, const float* __restrict__ GW,
    const float* __restrict__ GB,
    const unsigned short* __restrict__ A2,
    const unsigned short* __restrict__ B2,
    const float* __restrict__ bias2) {
    __shared__ alignas(16) unsigned short As[2][128 * 64];
    __shared__ alignas(16) unsigned short Bs[2][128 * 64];

    unsigned nwg = gridDim.x * gridDim.y;
    unsigned bid = blockIdx.y * gridDim.x + blockIdx.x;
    unsigned cpx = nwg >> 3;
    bid = (bid & 7u) * cpx + (bid >> 3);
    unsigned bx = bid % gridDim.x, by = bid / gridDim.x;
    size_t m0 = (size_t)by * 128;
    size_t nB = (size_t)bx * 128;
    size_t ncol0 = nB;

    const unsigned short* Ause = A;
    const unsigned short* Buse = B;
    const float* bias_use = bias;
    bool apply_gelu = false;
    if (MODE == EP_DUAL) {
        unsigned half = gridDim.x >> 1;
        if (bx >= half) {  // C-branch: h' @ Cw + Cb -> cols 1024..2047
            nB = (size_t)(bx - half) * 128;
            ncol0 = 1024 + nB;
            Ause = A2; Buse = B2; bias_use = bias2;
        } else {
            apply_gelu = true;
        }
    }

    int tid = threadIdx.x;
    int lane = tid & 63, w = tid >> 6;
    int wr = w >> 1, wc = w & 1;
    int cif = lane & 15;
    int rif = (lane >> 4) << 2;

    f32x4 acc[4][4];
#pragma unroll
    for (int i = 0; i < 4; ++i)
#pragma unroll
        for (int j = 0; j < 4; ++j)
#pragma unroll
            for (int r = 0; r < 4; ++r) acc[i][j][r] = 0.f;

    const unsigned short* Ablk = Ause + m0 * lda;
    const unsigned short* Bblk = Buse + nB * ldb;
    int srccol = ((lane & 7) ^ (lane >> 3)) * 8;
    int srow = w * 32 + (lane >> 3);
    int nkt = K >> 6;

    auto stage = [&](int buf, int kt) {
        int k0 = kt << 6;
        unsigned short* la = &As[buf][w * 2048];
        unsigned short* lb = &Bs[buf][w * 2048];
#pragma unroll
        for (int i = 0; i < 4; ++i) {
            __builtin_amdgcn_global_load_lds(
                (const AS1 void*)(Ablk + (size_t)(srow + i * 8) * lda + k0 + srccol),
                (AS3 void*)(la + i * 512), 16, 0, 0);
            __builtin_amdgcn_global_load_lds(
                (const AS1 void*)(Bblk + (size_t)(srow + i * 8) * ldb + k0 + srccol),
                (AS3 void*)(lb + i * 512), 16, 0, 0);
        }
    };

    stage(0, 0);
    __syncthreads();

    for (int kt = 0; kt < nkt; ++kt) {
        int cur = kt & 1;
        if (kt + 1 < nkt) stage(cur ^ 1, kt + 1);

        const bf16x8* Ap = reinterpret_cast<const bf16x8*>(As[cur]);
        const bf16x8* Bp = reinterpret_cast<const bf16x8*>(Bs[cur]);
#pragma unroll
        for (int kk = 0; kk < 2; ++kk) {
            bf16x8 af[4], bfr[4];
#pragma unroll
            for (int mi = 0; mi < 4; ++mi) {
                int row = wr * 64 + mi * 16 + (lane & 15);
                int slot = ((kk << 2) + (lane >> 4)) ^ (row & 7);
                af[mi] = Ap[row * 8 + slot];
            }
#pragma unroll
            for (int ni = 0; ni < 4; ++ni) {
                int row = wc * 64 + ni * 16 + (lane & 15);
                int slot = ((kk << 2) + (lane >> 4)) ^ (row & 7);
                bfr[ni] = Bp[row * 8 + slot];
            }
#pragma unroll
            for (int mi = 0; mi < 4; ++mi)
#pragma unroll
                for (int ni = 0; ni < 4; ++ni)
                    acc[mi][ni] = __builtin_amdgcn_mfma_f32_16x16x32_bf16(
                        af[mi], bfr[ni], acc[mi][ni], 0, 0, 0);
        }
        __syncthreads();
    }

    if (MODE == EP_PRELU_GN) {
        float* Cf = (float*)Cv;
        float pbv[4], pav[4], gwv[4], gbv[4];
        size_t gcolv[4];
#pragma unroll
        for (int ni = 0; ni < 4; ++ni) {
            gcolv[ni] = ncol0 + wc * 64 + ni * 16 + cif;
            pbv[ni] = bias[gcolv[ni]];
            pav[ni] = PA[gcolv[ni]];
            gwv[ni] = GW[gcolv[ni]];
            gbv[ni] = GB[gcolv[ni]];
        }
#pragma unroll
        for (int mi = 0; mi < 4; ++mi) {
#pragma unroll
            for (int ni = 0; ni < 4; ++ni)
#pragma unroll
                for (int r = 0; r < 4; ++r) {
                    float v = acc[mi][ni][r] + pbv[ni];
                    acc[mi][ni][r] = v >= 0.f ? v : pav[ni] * v;
                }
#pragma unroll
            for (int p = 0; p < 2; ++p) {
                float s[4], ss[4];
#pragma unroll
                for (int r = 0; r < 4; ++r) {
                    float a0 = acc[mi][2 * p][r], a1 = acc[mi][2 * p + 1][r];
                    s[r] = a0 + a1;
                    ss[r] = a0 * a0 + a1 * a1;
                }
#pragma unroll
                for (int msk = 1; msk < 16; msk <<= 1)
#pragma unroll
                    for (int r = 0; r < 4; ++r) {
                        s[r] += __shfl_xor(s[r], msk);
                        ss[r] += __shfl_xor(ss[r], msk);
                    }
#pragma unroll
                for (int r = 0; r < 4; ++r) {
                    float mu = s[r] * (1.f / 32.f);
                    float inv = rsqrtf(ss[r] * (1.f / 32.f) - mu * mu + 1e-5f);
                    size_t grow = m0 + wr * 64 + mi * 16 + rif + r;
#pragma unroll
                    for (int q = 0; q < 2; ++q) {
                        int ni = 2 * p + q;
                        Cf[grow * (size_t)ldc + gcolv[ni]] =
                            (acc[mi][ni][r] - mu) * inv * gwv[ni] + gbv[ni];
                    }
                }
            }
        }
        return;
    }

#pragma unroll
    for (int mi = 0; mi < 4; ++mi) {
#pragma unroll
        for (int ni = 0; ni < 4; ++ni) {
            size_t gcol = ncol0 + wc * 64 + ni * 16 + cif;
            size_t bcol = nB + wc * 64 + ni * 16 + cif;
            float bval = bias_use ? bias_use[bcol] : 0.f;
#pragma unroll
            for (int r = 0; r < 4; ++r) {
                size_t grow = m0 + wr * 64 + mi * 16 + rif + r;
                float val = acc[mi][ni][r] + bval;
                if (MODE == EP_DUAL && apply_gelu)
                    val = 0.5f * val * (1.f + erff(val * 0.70710678118654752f));
                ((unsigned short*)Cv)[grow * (size_t)ldc + gcol] = f2bf(val);
            }
        }
    }
}

extern "C" void kernel_launch(void* const* d_in, const int* in_sizes, int n_in,
                              void* d_out, int out_size, void* d_ws, size_t ws_size,
                              hipStream_t stream) {
    constexpr int Nn = 8192, IND = 512, INTER = 512, HID = 1024, OUTD = 512;
    const float* h   = (const float*)d_in[0];
    const float* Dm  = (const float*)d_in[1];
    const float* hp  = (const float*)d_in[2];
    const float* Qw  = (const float*)d_in[3];
    const float* Qb  = (const float*)d_in[4];
    const float* Kw  = (const float*)d_in[5];
    const float* Kb  = (const float*)d_in[6];
    const float* Vw  = (const float*)d_in[7];
    const float* Vb  = (const float*)d_in[8];
    const float* Rw  = (const float*)d_in[9];
    const float* Rb  = (const float*)d_in[10];
    const float* Cw  = (const float*)d_in[11];
    const float* Cb  = (const float*)d_in[12];
    const float* Pw  = (const float*)d_in[13];
    const float* Pb  = (const float*)d_in[14];
    const float* pa  = (const float*)d_in[15];
    const float* gwt = (const float*)d_in[16];
    const float* gbt = (const float*)d_in[17];
    (void)in_sizes; (void)n_in; (void)out_size; (void)ws_size;

    char* ws = (char*)d_ws;
    size_t cur = 0;
    auto alloc = [&](size_t bytes) -> void* {
        void* p = ws + cur;
        cur += (bytes + 255) & ~(size_t)255;
        return p;
    };
    unsigned short* h_bf   = (unsigned short*)alloc((size_t)Nn * IND * 2);
    unsigned short* hp_bf  = (unsigned short*)alloc((size_t)Nn * OUTD * 2);
    unsigned short* QKVwT  = (unsigned short*)alloc((size_t)3 * INTER * IND * 2);
    float*          qkvb   = (float*)alloc((size_t)3 * INTER * 4);
    unsigned short* RwT    = (unsigned short*)alloc((size_t)INTER * HID * 2);
    unsigned short* CwT    = (unsigned short*)alloc((size_t)OUTD * HID * 2);
    unsigned short* PwT    = (unsigned short*)alloc((size_t)2 * HID * OUTD * 2);
    unsigned short* QKVm   = (unsigned short*)alloc((size_t)Nn * 3 * INTER * 2);
    unsigned short* VTm    = (unsigned short*)alloc((size_t)Nn * INTER * 2);
    unsigned short* Sm     = (unsigned short*)alloc((size_t)Nn * Nn * 2);      // 134 MB scores
    float*          hret32 = (float*)alloc((size_t)4 * Nn * INTER * 4);        // K-split partials
    unsigned short* hretbf = (unsigned short*)alloc((size_t)Nn * INTER * 2);
    unsigned short* comb   = Sm;  // overlay: combined (8192x2048 bf16) over dead scores

    unsigned short* Qm = QKVm;
    unsigned short* Km = QKVm + INTER;
    unsigned short* Vm = QKVm + 2 * INTER;
    const int ldqkv = 3 * INTER;

    dim3 tb(32, 8);
    int n8 = Nn * IND / 8;
    cast2_kernel<<<dim3(n8 / 256, 2), 256, 0, stream>>>(h, hp, h_bf, hp_bf, n8);

    TD6 t6;
    t6.d[0] = {Qw, QKVwT,                          INTER, IND,     16, 16};
    t6.d[1] = {Kw, QKVwT + (size_t)INTER * IND,    INTER, IND,     16, 16};
    t6.d[2] = {Vw, QKVwT + (size_t)2 * INTER * IND,INTER, IND,     16, 16};
    t6.d[3] = {Rw, RwT,                            HID,   INTER,   32, 16};
    t6.d[4] = {Cw, CwT,                            HID,   OUTD,    32, 16};
    t6.d[5] = {Pw, PwT,                            OUTD,  2 * HID, 16, 64};
    multi_transpose_kernel<<<dim3(32, 64, 6), tb, 0, stream>>>(t6);
    concat_bias_kernel<<<6, 256, 0, stream>>>(Qb, Kb, Vb, qkvb);

    // fused QKV projection: (8192 x 1536) = h @ [Qw|Kw|Vw] + [Qb|Kb|Vb]
    gemm_bt_kernel<EP_BF16_BIAS><<<dim3(3 * INTER / 128, Nn / 128), 256, 0, stream>>>(
        h_bf, IND, QKVwT, IND, QKVm, ldqkv, IND, qkvb,
        nullptr, nullptr, nullptr, nullptr, nullptr, nullptr);
    transpose_bf16_kernel<<<dim3(INTER / 32, Nn / 32), tb, 0, stream>>>(Vm, ldqkv, VTm, Nn);

    // stage2: scores = D .* (Q K^T), full 8192x8192 bf16  [8-phase 256^2]
    gemm8p_kernel<P8_DMUL><<<dim3(Nn / 256, Nn / 256), 512, 0, stream>>>(
        Qm, ldqkv, Km, ldqkv, Sm, Nn, INTER, Dm, Nn, 0);

    // stage3: hret = scores @ V, K-split x4 into fp32 partials  [8-phase 256^2]
    gemm8p_kernel<P8_F32><<<dim3(OUTD / 256, Nn / 256, 4), 512, 0, stream>>>(
        Sm, Nn, VTm, Nn, hret32, INTER, Nn / 4, nullptr, 0, (size_t)Nn * INTER);
    sum4_cast_kernel<<<(Nn * INTER / 8) / 256, 256, 0, stream>>>(
        hret32, (size_t)Nn * INTER, hretbf, Nn * INTER / 8);

    // combined[:, :1024] = gelu(hret @ Rw + Rb) ; combined[:, 1024:] = h' @ Cw + Cb
    gemm_bt_kernel<EP_DUAL><<<dim3(2 * HID / 128, Nn / 128), 256, 0, stream>>>(
        hretbf, INTER, RwT, INTER, comb, 2 * HID, INTER, Rb,
        nullptr, nullptr, nullptr, hp_bf, CwT, Cb);

    // x = combined @ Pw + Pb -> PReLU -> GroupNorm -> d_out (fp32)
    gemm_bt_kernel<EP_PRELU_GN><<<dim3(OUTD / 128, Nn / 128), 256, 0, stream>>>(
        comb, 2 * HID, PwT, 2 * HID, d_out, OUTD, 2 * HID, Pb,
        pa, gwt, gbt, nullptr, nullptr, nullptr);
}